// Round 1
// baseline (3271.775 us; speedup 1.0000x reference)
//
#include <hip/hip_runtime.h>

#define T_ 5
#define C_ 3
#define H_ 128
#define W_ 128
#define HW_ (H_*W_)
#define WS_ 9
#define W2_ 81           // WS*WS
#define K_ 10
#define QN_ (T_*H_*W_)   // 81920
#define NSLOTS 1024
#define TOTAL_SEL (QN_ * 2 * K_)   // 1638400

__device__ __forceinline__ int clampi(int v, int hi) {
    return v < 0 ? 0 : (v > hi ? hi : v);
}

// One wave (64 lanes) per (q, s) pair. 4 waves / 256-thread block.
__global__ __launch_bounds__(256) void dnls_main(
    const float* __restrict__ noisy,
    const float* __restrict__ deno,
    const float* __restrict__ fflow,
    const float* __restrict__ bflow,
    float* __restrict__ acc)
{
    __shared__ float sQ[4][152];   // query patch (deno), layout [ch*49 + o]
    __shared__ float sP[4][64];    // refine partial sums

    const int wave = threadIdx.x >> 6;
    const int lane = threadIdx.x & 63;
    const int wsid = blockIdx.x * 4 + wave;   // 0 .. 163839
    const int q = wsid >> 1;
    const int s = wsid & 1;

    const int qt = q / HW_;
    const int qr = q - qt * HW_;
    const int qy = qr >> 7;     // / W_
    const int qx = qr & 127;    // % W_

    // time index of candidate frame
    const int ct = (s == 0) ? (qt + 1 < T_ ? qt + 1 : T_ - 1)
                            : (qt - 1 > 0 ? qt - 1 : 0);

    // flow: [1,T,2,H,W]; channel 0 = x, channel 1 = y. round half-to-even (rintf).
    const float* flow = (s == 0) ? fflow : bflow;
    const int fidx = (qt * 2 * H_ + qy) * W_ + qx;
    const int cen_x = qx + (int)rintf(flow[fidx]);
    const int cen_y = qy + (int)rintf(flow[fidx + HW_]);

    // ---- load query patch (deno) into LDS ----
    for (int i = lane; i < 147; i += 64) {
        int ch = i / 49;
        int o  = i - ch * 49;
        int dy = o / 7 - 3;
        int dx = o - (o / 7) * 7 - 3;
        int yy = clampi(qy + dy, H_ - 1);
        int xx = clampi(qx + dx, W_ - 1);
        sQ[wave][i] = deno[((qt * C_ + ch) * H_ + yy) * W_ + xx];
    }
    __syncthreads();

    // ---- d0: patch SSD for candidates w = lane, lane + 64 ----
    const float* cb = deno + (size_t)ct * C_ * HW_;   // candidate frame base (srch = deno)
    float dist[2];
    #pragma unroll
    for (int ci = 0; ci < 2; ++ci) {
        const int w = lane + 64 * ci;
        float d = 3.0e38f;
        if (w < W2_) {
            const int wy = w / WS_ - 4;
            const int wx = w - (w / WS_) * WS_ - 4;
            const int by = clampi(cen_y + wy, H_ - 1);
            const int bx = clampi(cen_x + wx, W_ - 1);
            d = 0.f;
            int o = 0;
            for (int dy = -3; dy <= 3; ++dy) {
                const int yy = clampi(by + dy, H_ - 1);
                const float* row = cb + yy * W_;
                #pragma unroll
                for (int dx = -3; dx <= 3; ++dx, ++o) {
                    const int xx = clampi(bx + dx, W_ - 1);
                    float a0 = sQ[wave][o]      - row[xx];
                    float a1 = sQ[wave][49 + o] - row[HW_ + xx];
                    float a2 = sQ[wave][98 + o] - row[2 * HW_ + xx];
                    d += a0 * a0 + a1 * a1 + a2 * a2;
                }
            }
        }
        dist[ci] = d;
    }

    // ---- top-K (K smallest d0, ties -> lower window index, matching lax.top_k) ----
    // key = (dist_bits << 32) | w ; non-negative fp32 orders as uint.
    unsigned long long k0 = ((unsigned long long)__float_as_uint(dist[0]) << 32) | (unsigned)lane;
    unsigned long long k1 = ((unsigned long long)__float_as_uint(dist[1]) << 32) | (unsigned)(lane + 64);

    const int lane_mod10 = lane % 10;
    float myD = 0.f;   // selected distance for this lane's refine work
    int   myW = 0;     // selected window index

    for (int k = 0; k < K_; ++k) {
        unsigned long long m = (k0 < k1) ? k0 : k1;
        #pragma unroll
        for (int off = 32; off >= 1; off >>= 1) {
            unsigned long long o = __shfl_xor(m, off, 64);
            m = (o < m) ? o : m;
        }
        // keys are unique (w embedded) -> exactly one owner removes it
        if (m == k0) k0 = ~0ULL;
        if (m == k1) k1 = ~0ULL;
        if (lane < 60 && lane_mod10 == k) {
            myD = __uint_as_float((unsigned)(m >> 32));
            myW = (int)(unsigned)(m & 0xffffffffu);
        }
    }

    // ---- refine: dref = SSD(deno query patch, noisy candidate patch) ----
    // lanes 0..59: sel = lane%10, part = lane/10; part covers offsets o = part, part+6, ...
    float partial = 0.f;
    if (lane < 60) {
        const int wy = myW / WS_ - 4;
        const int wx = myW - (myW / WS_) * WS_ - 4;
        const int by = clampi(cen_y + wy, H_ - 1);
        const int bx = clampi(cen_x + wx, W_ - 1);
        const int part = lane / 10;
        const float* nb = noisy + (size_t)ct * C_ * HW_;
        for (int o = part; o < 49; o += 6) {
            const int dy = o / 7 - 3;
            const int dx = o - (o / 7) * 7 - 3;
            const int yy = clampi(by + dy, H_ - 1);
            const int xx = clampi(bx + dx, W_ - 1);
            const float* p = nb + yy * W_ + xx;
            float a0 = sQ[wave][o]      - p[0];
            float a1 = sQ[wave][49 + o] - p[HW_];
            float a2 = sQ[wave][98 + o] - p[2 * HW_];
            partial += a0 * a0 + a1 * a1 + a2 * a2;
        }
    }
    sP[wave][lane] = partial;
    __syncthreads();

    float contrib = 0.f;
    if (lane < K_) {
        float dref = sP[wave][lane]      + sP[wave][lane + 10] + sP[wave][lane + 20]
                   + sP[wave][lane + 30] + sP[wave][lane + 40] + sP[wave][lane + 50];
        // mask = (d0k / (ps*ps*C) < 0.5)
        float mask = ((myD / 147.0f) < 0.5f) ? 1.f : 0.f;
        contrib = mask * dref;
    }
    // wave sum (lanes >= K_ hold 0)
    #pragma unroll
    for (int off = 32; off >= 1; off >>= 1)
        contrib += __shfl_xor(contrib, off, 64);

    if (lane == 0)
        atomicAdd(&acc[wsid & (NSLOTS - 1)], contrib * (1.0f / (float)TOTAL_SEL));
}

__global__ __launch_bounds__(64) void dnls_reduce(const float* __restrict__ acc,
                                                  float* __restrict__ out)
{
    const int lane = threadIdx.x;
    float v = 0.f;
    for (int i = lane; i < NSLOTS; i += 64) v += acc[i];
    #pragma unroll
    for (int off = 32; off >= 1; off >>= 1)
        v += __shfl_xor(v, off, 64);
    if (lane == 0) out[0] = v;
}

extern "C" void kernel_launch(void* const* d_in, const int* in_sizes, int n_in,
                              void* d_out, int out_size, void* d_ws, size_t ws_size,
                              hipStream_t stream) {
    const float* noisy = (const float*)d_in[0];
    // d_in[1] = clean (unused)
    const float* deno  = (const float*)d_in[2];
    const float* fflow = (const float*)d_in[3];
    const float* bflow = (const float*)d_in[4];
    // d_in[5] = curr_epoch (always 0 -> ps = 7, hardcoded)
    float* out = (float*)d_out;
    float* acc = (float*)d_ws;

    hipMemsetAsync(acc, 0, NSLOTS * sizeof(float), stream);

    const int nblocks = (QN_ * 2) / 4;   // one wave per (q,s), 4 waves/block
    dnls_main<<<nblocks, 256, 0, stream>>>(noisy, deno, fflow, bflow, acc);
    dnls_reduce<<<1, 64, 0, stream>>>(acc, out);
}

// Round 2
// 2595.750 us; speedup vs baseline: 1.2604x; 1.2604x over previous
//
#include <hip/hip_runtime.h>

#define T_ 5
#define C_ 3
#define H_ 128
#define W_ 128
#define HW_ (H_*W_)
#define WS_ 9
#define W2_ 81           // WS*WS
#define K_ 10
#define QN_ (T_*H_*W_)   // 81920
#define NSLOTS 1024
#define TOTAL_SEL (QN_ * 2 * K_)   // 1638400
#define R_ 15            // staged region side (window 9 + patch 7 - 1)
#define RR_ 225          // R_*R_

__device__ __forceinline__ int clampi(int v, int hi) {
    return v < 0 ? 0 : (v > hi ? hi : v);
}

// Build per-lane packed row/col LDS offsets for window w (0..80).
// Honors the reference's DOUBLE clamp: row = clamp(clamp(cen+wy')+dy).
// Each nibble j of rp/cp = (clamped index for dy=j-3) - rmin, in [0,14].
__device__ __forceinline__ void mkpacks(int cen_y, int cen_x, int w, int rmin, int cmin,
                                        unsigned& rp, unsigned& cp) {
    const int by = clampi(cen_y + w / WS_ - 4, H_ - 1);
    const int bx = clampi(cen_x + w - (w / WS_) * WS_ - 4, W_ - 1);
    unsigned r = 0, c = 0;
    #pragma unroll
    for (int j = 0; j < 7; ++j) {
        r |= (unsigned)(clampi(by + j - 3, H_ - 1) - rmin) << (4 * j);
        c |= (unsigned)(clampi(bx + j - 3, W_ - 1) - cmin) << (4 * j);
    }
    rp = r; cp = c;
}

// One wave per (q, s). 4 waves / block.
__global__ __launch_bounds__(256, 4) void dnls_main(
    const float* __restrict__ noisy,
    const float* __restrict__ deno,
    const float* __restrict__ fflow,
    const float* __restrict__ bflow,
    float* __restrict__ acc)
{
    __shared__ float sC[4][C_ * RR_];   // candidate region (deno, frame ct)
    __shared__ float sN[4][C_ * RR_];   // refine region   (noisy, frame ct)
    __shared__ float sQ[4][148];        // query patch (deno), [ch*49 + o]
    __shared__ float sP[4][64];         // refine partials

    const int wave = threadIdx.x >> 6;
    const int lane = threadIdx.x & 63;
    const int wsid = blockIdx.x * 4 + wave;
    const int q = wsid >> 1;
    const int s = wsid & 1;

    const int qt = q / HW_;
    const int qr = q - qt * HW_;
    const int qy = qr >> 7;
    const int qx = qr & 127;

    const int ct = (s == 0) ? (qt + 1 < T_ ? qt + 1 : T_ - 1)
                            : (qt - 1 > 0 ? qt - 1 : 0);

    const float* flow = (s == 0) ? fflow : bflow;
    const int fidx = (qt * 2 * H_ + qy) * W_ + qx;
    const int cen_x = qx + (int)rintf(flow[fidx]);
    const int cen_y = qy + (int)rintf(flow[fidx + HW_]);

    // ---- stage query patch (deno @ qt) ----
    for (int i = lane; i < 147; i += 64) {
        int ch = i / 49;
        int o  = i - ch * 49;
        int dy = o / 7 - 3;
        int dx = o - (o / 7) * 7 - 3;
        int yy = clampi(qy + dy, H_ - 1);
        int xx = clampi(qx + dx, W_ - 1);
        sQ[wave][i] = deno[((qt * C_ + ch) * H_ + yy) * W_ + xx];
    }

    // ---- stage 15x15x3 candidate + refine regions ----
    const int rmin = clampi(cen_y - 7, H_ - 1);
    const int cmin = clampi(cen_x - 7, W_ - 1);
    const float* cfrm = deno  + (size_t)ct * C_ * HW_;
    const float* nfrm = noisy + (size_t)ct * C_ * HW_;
    for (int i = lane; i < C_ * RR_; i += 64) {
        int ch  = i / RR_;
        int rem = i - ch * RR_;
        int ry  = rem / R_;
        int rx  = rem - ry * R_;
        int sy = rmin + ry; if (sy > H_ - 1) sy = H_ - 1;
        int sx = cmin + rx; if (sx > W_ - 1) sx = W_ - 1;
        int gi = (ch * H_ + sy) * W_ + sx;
        sC[wave][i] = cfrm[gi];
        sN[wave][i] = nfrm[gi];
    }
    __syncthreads();

    const float* C0 = &sC[wave][0];
    const float* N0 = &sN[wave][0];
    const float* Q0 = &sQ[wave][0];

    // ---- pass 1: windows w = lane (0..63), full SSD per lane ----
    unsigned rp1, cp1;
    mkpacks(cen_y, cen_x, lane, rmin, cmin, rp1, cp1);
    float d1 = 0.f;
    #pragma unroll
    for (int dy = 0; dy < 7; ++dy) {
        const float* Crow = C0 + ((rp1 >> (4 * dy)) & 15) * R_;
        const float* Qrow = Q0 + dy * 7;
        #pragma unroll
        for (int dx = 0; dx < 7; ++dx) {
            int a = (cp1 >> (4 * dx)) & 15;
            float a0 = Qrow[dx]      - Crow[a];
            float a1 = Qrow[49 + dx] - Crow[RR_ + a];
            float a2 = Qrow[98 + dx] - Crow[2 * RR_ + a];
            d1 += a0 * a0 + a1 * a1 + a2 * a2;
        }
    }

    // ---- pass 2: windows 64..80, 3 lanes per window (parts 0..2) ----
    float d2 = 0.f;
    const int w2   = 64 + lane / 3;          // valid for lane < 51
    const int part = lane - (lane / 3) * 3;
    unsigned rp2 = 0, cp2 = 0;
    if (lane < 51) {
        mkpacks(cen_y, cen_x, w2, rmin, cmin, rp2, cp2);
        for (int o = part; o < 49; o += 3) {
            int dyi = o / 7;
            int dxi = o - dyi * 7;
            const float* Crow = C0 + ((rp2 >> (4 * dyi)) & 15) * R_;
            int a = (cp2 >> (4 * dxi)) & 15;
            float a0 = Q0[o]      - Crow[a];
            float a1 = Q0[49 + o] - Crow[RR_ + a];
            float a2 = Q0[98 + o] - Crow[2 * RR_ + a];
            d2 += a0 * a0 + a1 * a1 + a2 * a2;
        }
    }
    // gather window sums (part0+part1+part2, deterministic order)
    const int base3 = lane * 3;  // for lane < 17: lanes base3, base3+1, base3+2
    float dd = __shfl(d2, base3 < 64 ? base3 : 0)
             + __shfl(d2, base3 + 1 < 64 ? base3 + 1 : 0)
             + __shfl(d2, base3 + 2 < 64 ? base3 + 2 : 0);

    // ---- top-K (smallest d0; ties -> lower window index) ----
    unsigned long long k0 = ((unsigned long long)__float_as_uint(d1) << 32) | (unsigned)lane;
    unsigned long long k1 = (lane < 17)
        ? ((((unsigned long long)__float_as_uint(dd)) << 32) | (unsigned)(64 + lane))
        : ~0ULL;

    const int lane_mod10 = lane % 10;
    float myD = 0.f;
    int   myW = 0;

    for (int k = 0; k < K_; ++k) {
        unsigned long long m = (k0 < k1) ? k0 : k1;
        #pragma unroll
        for (int off = 32; off >= 1; off >>= 1) {
            unsigned long long o = __shfl_xor(m, off, 64);
            m = (o < m) ? o : m;
        }
        if (m == k0) k0 = ~0ULL;
        if (m == k1) k1 = ~0ULL;
        if (lane < 60 && lane_mod10 == k) {
            myD = __uint_as_float((unsigned)(m >> 32));
            myW = (int)(unsigned)(m & 0xffffffffu);
        }
    }

    // ---- fetch packs of the selected window from its owner lane ----
    int ia = myW & 63;                         // owner if myW < 64
    int ib = myW >= 64 ? (myW - 64) * 3 : 0;   // owner if myW >= 64
    unsigned rpa = __shfl(rp1, ia), cpa = __shfl(cp1, ia);
    unsigned rpb = __shfl(rp2, ib), cpb = __shfl(cp2, ib);
    unsigned rpR = (myW < 64) ? rpa : rpb;
    unsigned cpR = (myW < 64) ? cpa : cpb;

    // ---- refine: SSD(deno query patch, noisy candidate patch) from LDS ----
    float partial = 0.f;
    if (lane < 60) {
        const int rpart = lane / 10;   // 0..5
        for (int o = rpart; o < 49; o += 6) {
            int dyi = o / 7;
            int dxi = o - dyi * 7;
            const float* Nrow = N0 + ((rpR >> (4 * dyi)) & 15) * R_;
            int a = (cpR >> (4 * dxi)) & 15;
            float a0 = Q0[o]      - Nrow[a];
            float a1 = Q0[49 + o] - Nrow[RR_ + a];
            float a2 = Q0[98 + o] - Nrow[2 * RR_ + a];
            partial += a0 * a0 + a1 * a1 + a2 * a2;
        }
    }
    sP[wave][lane] = partial;
    __syncthreads();

    float contrib = 0.f;
    if (lane < K_) {
        float dref = sP[wave][lane]      + sP[wave][lane + 10] + sP[wave][lane + 20]
                   + sP[wave][lane + 30] + sP[wave][lane + 40] + sP[wave][lane + 50];
        float mask = ((myD / 147.0f) < 0.5f) ? 1.f : 0.f;
        contrib = mask * dref;
    }
    #pragma unroll
    for (int off = 32; off >= 1; off >>= 1)
        contrib += __shfl_xor(contrib, off, 64);

    if (lane == 0)
        atomicAdd(&acc[wsid & (NSLOTS - 1)], contrib * (1.0f / (float)TOTAL_SEL));
}

__global__ __launch_bounds__(64) void dnls_reduce(const float* __restrict__ acc,
                                                  float* __restrict__ out)
{
    const int lane = threadIdx.x;
    float v = 0.f;
    for (int i = lane; i < NSLOTS; i += 64) v += acc[i];
    #pragma unroll
    for (int off = 32; off >= 1; off >>= 1)
        v += __shfl_xor(v, off, 64);
    if (lane == 0) out[0] = v;
}

extern "C" void kernel_launch(void* const* d_in, const int* in_sizes, int n_in,
                              void* d_out, int out_size, void* d_ws, size_t ws_size,
                              hipStream_t stream) {
    const float* noisy = (const float*)d_in[0];
    const float* deno  = (const float*)d_in[2];
    const float* fflow = (const float*)d_in[3];
    const float* bflow = (const float*)d_in[4];
    float* out = (float*)d_out;
    float* acc = (float*)d_ws;

    hipMemsetAsync(acc, 0, NSLOTS * sizeof(float), stream);

    const int nblocks = (QN_ * 2) / 4;
    dnls_main<<<nblocks, 256, 0, stream>>>(noisy, deno, fflow, bflow, acc);
    dnls_reduce<<<1, 64, 0, stream>>>(acc, out);
}

// Round 3
// 1982.340 us; speedup vs baseline: 1.6505x; 1.3094x over previous
//
#include <hip/hip_runtime.h>

#define T_ 5
#define C_ 3
#define H_ 128
#define W_ 128
#define HW_ (H_*W_)
#define WS_ 9
#define W2_ 81           // WS*WS
#define K_ 10
#define QN_ (T_*H_*W_)   // 81920
#define NSLOTS 1024
#define TOTAL_SEL (QN_ * 2 * K_)   // 1638400
#define R_ 15            // staged region side (window 9 + patch 7 - 1)
#define RS_ 17           // padded row stride (bank-conflict spread)
#define RRS_ (R_*RS_)    // 255 floats per channel plane

__device__ __forceinline__ int clampi(int v, int hi) {
    return v < 0 ? 0 : (v > hi ? hi : v);
}

// Packed per-patch-offset clamped LDS indices for window w (0..80).
// Honors the reference's DOUBLE clamp: row = clamp(clamp(cen+wy')+dy).
// Nibble j of rp/cp = clamped index (row-rmin or col-cmin) for offset j-3.
__device__ __forceinline__ void mkpacks(int cen_y, int cen_x, int w, int rmin, int cmin,
                                        unsigned& rp, unsigned& cp) {
    const int by = clampi(cen_y + w / WS_ - 4, H_ - 1);
    const int bx = clampi(cen_x + w - (w / WS_) * WS_ - 4, W_ - 1);
    unsigned r = 0, c = 0;
    #pragma unroll
    for (int j = 0; j < 7; ++j) {
        r |= (unsigned)(clampi(by + j - 3, H_ - 1) - rmin) << (4 * j);
        c |= (unsigned)(clampi(bx + j - 3, W_ - 1) - cmin) << (4 * j);
    }
    rp = r; cp = c;
}

// One wave per (q, s). 4 waves / block.
// NOTE: no min-waves clause — (256,4) forced VGPR=64 with ~48KB/wave scratch
// spills = 12 GB of HBM traffic per dispatch (R2 post-mortem).
__global__ __launch_bounds__(256) void dnls_main(
    const float* __restrict__ noisy,
    const float* __restrict__ deno,
    const float* __restrict__ fflow,
    const float* __restrict__ bflow,
    float* __restrict__ acc)
{
    __shared__ float sC[4][C_ * RRS_];  // candidate region (deno @ ct), padded rows
    __shared__ float sN[4][C_ * RRS_];  // refine region (noisy @ ct)
    __shared__ float sQ[4][148];        // query patch (deno @ qt), [ch*49 + o]
    __shared__ float sP[4][64];         // refine partials

    const int wave = threadIdx.x >> 6;
    const int lane = threadIdx.x & 63;
    const int wsid = blockIdx.x * 4 + wave;
    const int q = wsid >> 1;
    const int s = wsid & 1;

    const int qt = q / HW_;
    const int qr = q - qt * HW_;
    const int qy = qr >> 7;
    const int qx = qr & 127;

    const int ct = (s == 0) ? (qt + 1 < T_ ? qt + 1 : T_ - 1)
                            : (qt - 1 > 0 ? qt - 1 : 0);

    const float* flow = (s == 0) ? fflow : bflow;
    const int fidx = (qt * 2 * H_ + qy) * W_ + qx;
    const int cen_x = qx + (int)rintf(flow[fidx]);
    const int cen_y = qy + (int)rintf(flow[fidx + HW_]);

    // ---- stage query patch (deno @ qt) ----
    for (int i = lane; i < 147; i += 64) {
        int ch = i / 49;
        int o  = i - ch * 49;
        int dy = o / 7 - 3;
        int dx = o - (o / 7) * 7 - 3;
        int yy = clampi(qy + dy, H_ - 1);
        int xx = clampi(qx + dx, W_ - 1);
        sQ[wave][i] = deno[((qt * C_ + ch) * H_ + yy) * W_ + xx];
    }

    // ---- stage 15x15x3 candidate + refine regions (padded row stride 17) ----
    const int rmin = clampi(cen_y - 7, H_ - 1);
    const int cmin = clampi(cen_x - 7, W_ - 1);
    const float* cfrm = deno  + (size_t)ct * C_ * HW_;
    const float* nfrm = noisy + (size_t)ct * C_ * HW_;
    for (int i = lane; i < C_ * R_ * R_; i += 64) {
        int ch  = i / (R_ * R_);
        int rem = i - ch * (R_ * R_);
        int ry  = rem / R_;
        int rx  = rem - ry * R_;
        int sy = rmin + ry; if (sy > H_ - 1) sy = H_ - 1;
        int sx = cmin + rx; if (sx > W_ - 1) sx = W_ - 1;
        int gi = (ch * H_ + sy) * W_ + sx;
        int li = ch * RRS_ + ry * RS_ + rx;
        sC[wave][li] = cfrm[gi];
        sN[wave][li] = nfrm[gi];
    }
    __syncthreads();

    const float* C0 = &sC[wave][0];
    const float* N0 = &sN[wave][0];
    const float* Q0 = &sQ[wave][0];

    // ---- pass 1: windows w = lane (0..63), full SSD per lane ----
    unsigned rp1, cp1;
    mkpacks(cen_y, cen_x, lane, rmin, cmin, rp1, cp1);
    float d1 = 0.f;
    #pragma unroll
    for (int dy = 0; dy < 7; ++dy) {
        const float* Crow = C0 + ((rp1 >> (4 * dy)) & 15) * RS_;
        const float* Qrow = Q0 + dy * 7;
        #pragma unroll
        for (int dx = 0; dx < 7; ++dx) {
            int a = (cp1 >> (4 * dx)) & 15;
            float a0 = Qrow[dx]      - Crow[a];
            float a1 = Qrow[49 + dx] - Crow[RRS_ + a];
            float a2 = Qrow[98 + dx] - Crow[2 * RRS_ + a];
            d1 += a0 * a0 + a1 * a1 + a2 * a2;
        }
    }

    // ---- pass 2: windows 64..80, 3 lanes per window (parts 0..2) ----
    float d2 = 0.f;
    const int w2   = 64 + lane / 3;          // valid for lane < 51
    const int part = lane - (lane / 3) * 3;
    unsigned rp2 = 0, cp2 = 0;
    if (lane < 51) {
        mkpacks(cen_y, cen_x, w2, rmin, cmin, rp2, cp2);
        for (int o = part; o < 49; o += 3) {
            int dyi = o / 7;
            int dxi = o - dyi * 7;
            const float* Crow = C0 + ((rp2 >> (4 * dyi)) & 15) * RS_;
            int a = (cp2 >> (4 * dxi)) & 15;
            float a0 = Q0[o]      - Crow[a];
            float a1 = Q0[49 + o] - Crow[RRS_ + a];
            float a2 = Q0[98 + o] - Crow[2 * RRS_ + a];
            d2 += a0 * a0 + a1 * a1 + a2 * a2;
        }
    }
    // gather window sums (part0+part1+part2, deterministic order)
    const int base3 = lane * 3;
    float dd = __shfl(d2, base3 < 64 ? base3 : 0)
             + __shfl(d2, base3 + 1 < 64 ? base3 + 1 : 0)
             + __shfl(d2, base3 + 2 < 64 ? base3 + 2 : 0);

    // ---- top-K (smallest d0; ties -> lower window index) ----
    unsigned long long k0 = ((unsigned long long)__float_as_uint(d1) << 32) | (unsigned)lane;
    unsigned long long k1 = (lane < 17)
        ? ((((unsigned long long)__float_as_uint(dd)) << 32) | (unsigned)(64 + lane))
        : ~0ULL;

    const int lane_mod10 = lane % 10;
    float myD = 0.f;
    int   myW = 0;

    for (int k = 0; k < K_; ++k) {
        unsigned long long m = (k0 < k1) ? k0 : k1;
        #pragma unroll
        for (int off = 32; off >= 1; off >>= 1) {
            unsigned long long o = __shfl_xor(m, off, 64);
            m = (o < m) ? o : m;
        }
        if (m == k0) k0 = ~0ULL;
        if (m == k1) k1 = ~0ULL;
        if (lane < 60 && lane_mod10 == k) {
            myD = __uint_as_float((unsigned)(m >> 32));
            myW = (int)(unsigned)(m & 0xffffffffu);
        }
    }

    // ---- fetch packs of the selected window from its owner lane ----
    int ia = myW & 63;
    int ib = myW >= 64 ? (myW - 64) * 3 : 0;
    unsigned rpa = __shfl(rp1, ia), cpa = __shfl(cp1, ia);
    unsigned rpb = __shfl(rp2, ib), cpb = __shfl(cp2, ib);
    unsigned rpR = (myW < 64) ? rpa : rpb;
    unsigned cpR = (myW < 64) ? cpa : cpb;

    // ---- refine: SSD(deno query patch, noisy candidate patch) from LDS ----
    float partial = 0.f;
    if (lane < 60) {
        const int rpart = lane / 10;   // 0..5
        for (int o = rpart; o < 49; o += 6) {
            int dyi = o / 7;
            int dxi = o - dyi * 7;
            const float* Nrow = N0 + ((rpR >> (4 * dyi)) & 15) * RS_;
            int a = (cpR >> (4 * dxi)) & 15;
            float a0 = Q0[o]      - Nrow[a];
            float a1 = Q0[49 + o] - Nrow[RRS_ + a];
            float a2 = Q0[98 + o] - Nrow[2 * RRS_ + a];
            partial += a0 * a0 + a1 * a1 + a2 * a2;
        }
    }
    sP[wave][lane] = partial;
    __syncthreads();

    float contrib = 0.f;
    if (lane < K_) {
        float dref = sP[wave][lane]      + sP[wave][lane + 10] + sP[wave][lane + 20]
                   + sP[wave][lane + 30] + sP[wave][lane + 40] + sP[wave][lane + 50];
        float mask = ((myD / 147.0f) < 0.5f) ? 1.f : 0.f;
        contrib = mask * dref;
    }
    #pragma unroll
    for (int off = 32; off >= 1; off >>= 1)
        contrib += __shfl_xor(contrib, off, 64);

    if (lane == 0)
        atomicAdd(&acc[wsid & (NSLOTS - 1)], contrib * (1.0f / (float)TOTAL_SEL));
}

__global__ __launch_bounds__(64) void dnls_reduce(const float* __restrict__ acc,
                                                  float* __restrict__ out)
{
    const int lane = threadIdx.x;
    float v = 0.f;
    for (int i = lane; i < NSLOTS; i += 64) v += acc[i];
    #pragma unroll
    for (int off = 32; off >= 1; off >>= 1)
        v += __shfl_xor(v, off, 64);
    if (lane == 0) out[0] = v;
}

extern "C" void kernel_launch(void* const* d_in, const int* in_sizes, int n_in,
                              void* d_out, int out_size, void* d_ws, size_t ws_size,
                              hipStream_t stream) {
    const float* noisy = (const float*)d_in[0];
    const float* deno  = (const float*)d_in[2];
    const float* fflow = (const float*)d_in[3];
    const float* bflow = (const float*)d_in[4];
    float* out = (float*)d_out;
    float* acc = (float*)d_ws;

    hipMemsetAsync(acc, 0, NSLOTS * sizeof(float), stream);

    const int nblocks = (QN_ * 2) / 4;
    dnls_main<<<nblocks, 256, 0, stream>>>(noisy, deno, fflow, bflow, acc);
    dnls_reduce<<<1, 64, 0, stream>>>(acc, out);
}

// Round 4
// 1570.102 us; speedup vs baseline: 2.0838x; 1.2626x over previous
//
#include <hip/hip_runtime.h>

#define T_ 5
#define C_ 3
#define H_ 128
#define W_ 128
#define HW_ (H_*W_)
#define WS_ 9
#define W2_ 81           // WS*WS
#define K_ 10
#define QN_ (T_*H_*W_)   // 81920
#define NSLOTS 1024
#define TOTAL_SEL (QN_ * 2 * K_)   // 1638400
#define R_ 15            // staged region side (window 9 + patch 7 - 1)
#define RS_ 17           // padded row stride in PIXELS (float4 each)

__device__ __forceinline__ int clampi(int v, int hi) {
    return v < 0 ? 0 : (v > hi ? hi : v);
}

// Packed per-patch-offset clamped LDS indices for window w (0..80).
// Honors the reference's DOUBLE clamp: row = clamp(clamp(cen+wy')+dy).
// Nibble j of rp/cp = clamped (row-rmin)/(col-cmin) for offset j-3, in [0,14].
__device__ __forceinline__ void mkpacks(int cen_y, int cen_x, int w, int rmin, int cmin,
                                        unsigned& rp, unsigned& cp) {
    const int by = clampi(cen_y + w / WS_ - 4, H_ - 1);
    const int bx = clampi(cen_x + w - (w / WS_) * WS_ - 4, W_ - 1);
    unsigned r = 0, c = 0;
    #pragma unroll
    for (int j = 0; j < 7; ++j) {
        r |= (unsigned)(clampi(by + j - 3, H_ - 1) - rmin) << (4 * j);
        c |= (unsigned)(clampi(bx + j - 3, W_ - 1) - cmin) << (4 * j);
    }
    rp = r; cp = c;
}

// One wave per (q, s). 4 waves / block.
// NOTE: no min-waves clause — (256,4) forced VGPR=64 with huge scratch spills
// (12 GB HBM traffic/dispatch, R2 post-mortem).
__global__ __launch_bounds__(256) void dnls_main(
    const float* __restrict__ noisy,
    const float* __restrict__ deno,
    const float* __restrict__ fflow,
    const float* __restrict__ bflow,
    float* __restrict__ acc)
{
    // channel-interleaved float4 (rgb+pad): 1 ds_read_b128 per pixel
    __shared__ float4 sC[4][R_ * RS_];   // candidate region (deno @ ct)
    __shared__ float4 sN[4][R_ * RS_];   // refine region (noisy @ ct)
    __shared__ float4 sQ[4][49];         // query patch (deno @ qt)

    const int wave = threadIdx.x >> 6;
    const int lane = threadIdx.x & 63;
    const int wsid = blockIdx.x * 4 + wave;
    const int q = wsid >> 1;
    const int s = wsid & 1;

    const int qt = q / HW_;
    const int qr = q - qt * HW_;
    const int qy = qr >> 7;
    const int qx = qr & 127;

    const int ct = (s == 0) ? (qt + 1 < T_ ? qt + 1 : T_ - 1)
                            : (qt - 1 > 0 ? qt - 1 : 0);

    const float* flow = (s == 0) ? fflow : bflow;
    const int fidx = (qt * 2 * H_ + qy) * W_ + qx;
    const int cen_x = qx + (int)rintf(flow[fidx]);
    const int cen_y = qy + (int)rintf(flow[fidx + HW_]);

    // ---- stage query patch (deno @ qt), interleaved ----
    if (lane < 49) {
        const int dy = lane / 7 - 3;
        const int dx = lane - (lane / 7) * 7 - 3;
        const int yy = clampi(qy + dy, H_ - 1);
        const int xx = clampi(qx + dx, W_ - 1);
        const float* p = deno + (size_t)qt * C_ * HW_ + yy * W_ + xx;
        sQ[wave][lane] = make_float4(p[0], p[HW_], p[2 * HW_], 0.f);
    }

    // ---- stage 15x15 candidate + refine regions, interleaved ----
    const int rmin = clampi(cen_y - 7, H_ - 1);
    const int cmin = clampi(cen_x - 7, W_ - 1);
    const float* cfrm = deno  + (size_t)ct * C_ * HW_;
    const float* nfrm = noisy + (size_t)ct * C_ * HW_;
    for (int i = lane; i < R_ * R_; i += 64) {
        const int ry = i / R_;
        const int rx = i - ry * R_;
        int sy = rmin + ry; if (sy > H_ - 1) sy = H_ - 1;
        int sx = cmin + rx; if (sx > W_ - 1) sx = W_ - 1;
        const int gi = sy * W_ + sx;
        const int li = ry * RS_ + rx;
        sC[wave][li] = make_float4(cfrm[gi], cfrm[HW_ + gi], cfrm[2 * HW_ + gi], 0.f);
        sN[wave][li] = make_float4(nfrm[gi], nfrm[HW_ + gi], nfrm[2 * HW_ + gi], 0.f);
    }
    __syncthreads();

    const float4* C4 = &sC[wave][0];
    const float4* N4 = &sN[wave][0];
    const float4* Q4 = &sQ[wave][0];

    // ---- pass 1: windows w = lane (0..63), full SSD per lane ----
    unsigned rp1, cp1;
    mkpacks(cen_y, cen_x, lane, rmin, cmin, rp1, cp1);
    float d1 = 0.f;
    for (int dy = 0; dy < 7; ++dy) {            // NOT unrolled: cap VGPR live window
        const float4* Crow = C4 + ((rp1 >> (4 * dy)) & 15) * RS_;
        const float4* Qrow = Q4 + dy * 7;
        #pragma unroll
        for (int dx = 0; dx < 7; ++dx) {
            float4 cv = Crow[(cp1 >> (4 * dx)) & 15];
            float4 qv = Qrow[dx];
            float a0 = qv.x - cv.x, a1 = qv.y - cv.y, a2 = qv.z - cv.z;
            d1 += a0 * a0 + a1 * a1 + a2 * a2;
        }
    }

    // ---- pass 2: windows 64..80, 3 lanes per window ----
    float d2 = 0.f;
    const int w2   = 64 + lane / 3;          // valid for lane < 51
    const int part = lane - (lane / 3) * 3;
    unsigned rp2 = 0, cp2 = 0;
    if (lane < 51) {
        mkpacks(cen_y, cen_x, w2, rmin, cmin, rp2, cp2);
        for (int o = part; o < 49; o += 3) {
            const int dyi = o / 7;
            const int dxi = o - dyi * 7;
            float4 cv = C4[((rp2 >> (4 * dyi)) & 15) * RS_ + ((cp2 >> (4 * dxi)) & 15)];
            float4 qv = Q4[o];
            float a0 = qv.x - cv.x, a1 = qv.y - cv.y, a2 = qv.z - cv.z;
            d2 += a0 * a0 + a1 * a1 + a2 * a2;
        }
    }
    const int base3 = lane * 3;
    float dd = __shfl(d2, base3 < 64 ? base3 : 0)
             + __shfl(d2, base3 + 1 < 64 ? base3 + 1 : 0)
             + __shfl(d2, base3 + 2 < 64 ? base3 + 2 : 0);

    // ---- top-K with 32-bit keys: (dist_bits & ~0x7F) | w ----
    // Monotone floor-quantization (2^-16 relative), unique (w in low 7 bits),
    // exact ties -> lower w (matches lax.top_k). Near-tie flips perturb the
    // output by ~1e-5 per flip — far under threshold.
    unsigned k0 = (__float_as_uint(d1) & 0xFFFFFF80u) | (unsigned)lane;
    unsigned k1 = (lane < 17)
        ? ((__float_as_uint(dd) & 0xFFFFFF80u) | (unsigned)(64 + lane))
        : 0xFFFFFFFFu;

    const int lane_mod10 = lane % 10;
    unsigned myKey = 0;

    for (int k = 0; k < K_; ++k) {
        unsigned m = (k0 < k1) ? k0 : k1;
        #pragma unroll
        for (int off = 32; off >= 1; off >>= 1) {
            unsigned o = __shfl_xor(m, off, 64);
            m = (o < m) ? o : m;
        }
        if (m == k0) k0 = 0xFFFFFFFFu;
        if (m == k1) k1 = 0xFFFFFFFFu;
        if (lane < 60 && lane_mod10 == k) myKey = m;
    }

    const int   myW = (int)(myKey & 0x7Fu);
    const float myD = __uint_as_float(myKey & 0xFFFFFF80u);

    // ---- fetch packs of the selected window from its owner lane ----
    const int ia = myW & 63;
    const int ib = myW >= 64 ? (myW - 64) * 3 : 0;
    unsigned rpa = __shfl(rp1, ia), cpa = __shfl(cp1, ia);
    unsigned rpb = __shfl(rp2, ib), cpb = __shfl(cp2, ib);
    const unsigned rpR = (myW < 64) ? rpa : rpb;
    const unsigned cpR = (myW < 64) ? cpa : cpb;

    // ---- refine: SSD(deno query, noisy candidate), mask applied per lane ----
    float partial = 0.f;
    if (lane < 60) {
        const int rpart = lane / 10;   // 0..5
        for (int o = rpart; o < 49; o += 6) {
            const int dyi = o / 7;
            const int dxi = o - dyi * 7;
            float4 nv = N4[((rpR >> (4 * dyi)) & 15) * RS_ + ((cpR >> (4 * dxi)) & 15)];
            float4 qv = Q4[o];
            float a0 = qv.x - nv.x, a1 = qv.y - nv.y, a2 = qv.z - nv.z;
            partial += a0 * a0 + a1 * a1 + a2 * a2;
        }
        // mask = (d0 / 147 < 0.5)  <=>  d0 < 73.5
        if (!(myD < 73.5f)) partial = 0.f;
    }
    // one 64-wide sum: sum_k mask_k * dref_k (order-free)
    #pragma unroll
    for (int off = 32; off >= 1; off >>= 1)
        partial += __shfl_xor(partial, off, 64);

    if (lane == 0)
        atomicAdd(&acc[wsid & (NSLOTS - 1)], partial * (1.0f / (float)TOTAL_SEL));
}

__global__ __launch_bounds__(64) void dnls_reduce(const float* __restrict__ acc,
                                                  float* __restrict__ out)
{
    const int lane = threadIdx.x;
    float v = 0.f;
    for (int i = lane; i < NSLOTS; i += 64) v += acc[i];
    #pragma unroll
    for (int off = 32; off >= 1; off >>= 1)
        v += __shfl_xor(v, off, 64);
    if (lane == 0) out[0] = v;
}

extern "C" void kernel_launch(void* const* d_in, const int* in_sizes, int n_in,
                              void* d_out, int out_size, void* d_ws, size_t ws_size,
                              hipStream_t stream) {
    const float* noisy = (const float*)d_in[0];
    const float* deno  = (const float*)d_in[2];
    const float* fflow = (const float*)d_in[3];
    const float* bflow = (const float*)d_in[4];
    float* out = (float*)d_out;
    float* acc = (float*)d_ws;

    hipMemsetAsync(acc, 0, NSLOTS * sizeof(float), stream);

    const int nblocks = (QN_ * 2) / 4;
    dnls_main<<<nblocks, 256, 0, stream>>>(noisy, deno, fflow, bflow, acc);
    dnls_reduce<<<1, 64, 0, stream>>>(acc, out);
}

// Round 5
// 627.515 us; speedup vs baseline: 5.2139x; 2.5021x over previous
//
#include <hip/hip_runtime.h>

#define T_ 5
#define C_ 3
#define H_ 128
#define W_ 128
#define HW_ (H_*W_)
#define WS_ 9
#define W2_ 81           // WS*WS
#define K_ 10
#define QN_ (T_*H_*W_)   // 81920
#define NSLOTS 1024
#define TOTAL_SEL (QN_ * 2 * K_)   // 1638400
#define R_ 15            // staged region side (window 9 + patch 7 - 1)
#define RS_ 17           // padded row stride in PIXELS (float4 each)

__device__ __forceinline__ int clampi(int v, int hi) {
    return v < 0 ? 0 : (v > hi ? hi : v);
}

// Packed per-patch-offset clamped LDS indices for window w (0..80).
// Honors the reference's DOUBLE clamp: row = clamp(clamp(cen+wy')+dy).
// Nibble j of rp/cp = clamped (row-rmin)/(col-cmin) for offset j-3, in [0,14].
__device__ __forceinline__ void mkpacks(int cen_y, int cen_x, int w, int rmin, int cmin,
                                        unsigned& rp, unsigned& cp) {
    const int by = clampi(cen_y + w / WS_ - 4, H_ - 1);
    const int bx = clampi(cen_x + w - (w / WS_) * WS_ - 4, W_ - 1);
    unsigned r = 0, c = 0;
    #pragma unroll
    for (int j = 0; j < 7; ++j) {
        r |= (unsigned)(clampi(by + j - 3, H_ - 1) - rmin) << (4 * j);
        c |= (unsigned)(clampi(bx + j - 3, W_ - 1) - cmin) << (4 * j);
    }
    rp = r; cp = c;
}

// One wave per (q, s). 4 waves / block.
// (256,3): cap VGPR at 168 -> 3 waves/SIMD. (256,4) forced 64 VGPR + massive
// spills (R2); uncapped gave 204 VGPR -> 2 waves/SIMD (R4).
__global__ __launch_bounds__(256, 3) void dnls_main(
    const float* __restrict__ noisy,
    const float* __restrict__ deno,
    const float* __restrict__ fflow,
    const float* __restrict__ bflow,
    float* __restrict__ acc)
{
    // channel-interleaved float4 (rgb+pad): 1 ds_read_b128 per pixel
    __shared__ float4 sC[4][R_ * RS_];   // candidate region (deno @ ct)
    __shared__ float4 sN[4][R_ * RS_];   // refine region (noisy @ ct)
    __shared__ float4 sQ[4][49];         // query patch (deno @ qt)

    const int wave = threadIdx.x >> 6;
    const int lane = threadIdx.x & 63;
    const int wsid = blockIdx.x * 4 + wave;
    const int q = wsid >> 1;
    const int s = wsid & 1;

    const int qt = q / HW_;
    const int qr = q - qt * HW_;
    const int qy = qr >> 7;
    const int qx = qr & 127;

    const int ct = (s == 0) ? (qt + 1 < T_ ? qt + 1 : T_ - 1)
                            : (qt - 1 > 0 ? qt - 1 : 0);

    const float* flow = (s == 0) ? fflow : bflow;
    const int fidx = (qt * 2 * H_ + qy) * W_ + qx;
    const int cen_x = qx + (int)rintf(flow[fidx]);
    const int cen_y = qy + (int)rintf(flow[fidx + HW_]);

    // ---- stage query patch (deno @ qt), interleaved ----
    if (lane < 49) {
        const int dy = lane / 7 - 3;
        const int dx = lane - (lane / 7) * 7 - 3;
        const int yy = clampi(qy + dy, H_ - 1);
        const int xx = clampi(qx + dx, W_ - 1);
        const float* p = deno + (size_t)qt * C_ * HW_ + yy * W_ + xx;
        sQ[wave][lane] = make_float4(p[0], p[HW_], p[2 * HW_], 0.f);
    }

    // ---- stage 15x15 candidate + refine regions, interleaved ----
    const int rmin = clampi(cen_y - 7, H_ - 1);
    const int cmin = clampi(cen_x - 7, W_ - 1);
    const float* cfrm = deno  + (size_t)ct * C_ * HW_;
    const float* nfrm = noisy + (size_t)ct * C_ * HW_;
    for (int i = lane; i < R_ * R_; i += 64) {
        const int ry = i / R_;
        const int rx = i - ry * R_;
        int sy = rmin + ry; if (sy > H_ - 1) sy = H_ - 1;
        int sx = cmin + rx; if (sx > W_ - 1) sx = W_ - 1;
        const int gi = sy * W_ + sx;
        const int li = ry * RS_ + rx;
        sC[wave][li] = make_float4(cfrm[gi], cfrm[HW_ + gi], cfrm[2 * HW_ + gi], 0.f);
        sN[wave][li] = make_float4(nfrm[gi], nfrm[HW_ + gi], nfrm[2 * HW_ + gi], 0.f);
    }
    __syncthreads();

    const float4* C4 = &sC[wave][0];
    const float4* N4 = &sN[wave][0];
    const float4* Q4 = &sQ[wave][0];

    // ---- pass 1: windows w = lane (0..63), full SSD per lane ----
    unsigned rp1, cp1;
    mkpacks(cen_y, cen_x, lane, rmin, cmin, rp1, cp1);
    // 3 per-channel accumulators: FMA ILP without holding 14 float4 live
    float s0 = 0.f, s1 = 0.f, s2 = 0.f;
    #pragma unroll 1
    for (int dy = 0; dy < 7; ++dy) {
        const float4* Crow = C4 + ((rp1 >> (4 * dy)) & 15) * RS_;
        const float4* Qrow = Q4 + dy * 7;
        #pragma unroll 4
        for (int dx = 0; dx < 7; ++dx) {
            float4 cv = Crow[(cp1 >> (4 * dx)) & 15];
            float4 qv = Qrow[dx];
            float a0 = qv.x - cv.x, a1 = qv.y - cv.y, a2 = qv.z - cv.z;
            s0 += a0 * a0; s1 += a1 * a1; s2 += a2 * a2;
        }
    }
    const float d1 = s0 + s1 + s2;

    // ---- pass 2: windows 64..80, 3 lanes per window ----
    float d2 = 0.f;
    const int w2   = 64 + lane / 3;          // valid for lane < 51
    const int part = lane - (lane / 3) * 3;
    if (lane < 51) {
        unsigned rp2, cp2;
        mkpacks(cen_y, cen_x, w2, rmin, cmin, rp2, cp2);
        float t0 = 0.f, t1 = 0.f, t2 = 0.f;
        #pragma unroll 1
        for (int o = part; o < 49; o += 3) {
            const int dyi = o / 7;
            const int dxi = o - dyi * 7;
            float4 cv = C4[((rp2 >> (4 * dyi)) & 15) * RS_ + ((cp2 >> (4 * dxi)) & 15)];
            float4 qv = Q4[o];
            float a0 = qv.x - cv.x, a1 = qv.y - cv.y, a2 = qv.z - cv.z;
            t0 += a0 * a0; t1 += a1 * a1; t2 += a2 * a2;
        }
        d2 = t0 + t1 + t2;
    }
    const int base3 = lane * 3;
    float dd = __shfl(d2, base3 < 64 ? base3 : 0)
             + __shfl(d2, base3 + 1 < 64 ? base3 + 1 : 0)
             + __shfl(d2, base3 + 2 < 64 ? base3 + 2 : 0);

    // ---- top-K with 32-bit keys: (dist_bits & ~0x7F) | w ----
    // Monotone floor-quantization (2^-16 relative), unique (w in low 7 bits),
    // exact ties -> lower w (matches lax.top_k).
    unsigned k0 = (__float_as_uint(d1) & 0xFFFFFF80u) | (unsigned)lane;
    unsigned k1 = (lane < 17)
        ? ((__float_as_uint(dd) & 0xFFFFFF80u) | (unsigned)(64 + lane))
        : 0xFFFFFFFFu;

    const int lane_mod10 = lane % 10;
    unsigned myKey = 0;

    for (int k = 0; k < K_; ++k) {
        unsigned m = (k0 < k1) ? k0 : k1;
        #pragma unroll
        for (int off = 32; off >= 1; off >>= 1) {
            unsigned o = __shfl_xor(m, off, 64);
            m = (o < m) ? o : m;
        }
        if (m == k0) k0 = 0xFFFFFFFFu;
        if (m == k1) k1 = 0xFFFFFFFFu;
        if (lane < 60 && lane_mod10 == k) myKey = m;
    }

    const int   myW = (int)(myKey & 0x7Fu);
    const float myD = __uint_as_float(myKey & 0xFFFFFF80u);

    // ---- refine: SSD(deno query, noisy candidate), mask applied per lane ----
    // Recompute the selected window's packs locally (~30 VALU) instead of
    // shuffling from owner lanes -> rp2/cp2 die before top-k (reg pressure).
    float partial = 0.f;
    if (lane < 60) {
        unsigned rpR, cpR;
        mkpacks(cen_y, cen_x, myW, rmin, cmin, rpR, cpR);
        const int rpart = lane / 10;   // 0..5
        float t0 = 0.f, t1 = 0.f, t2 = 0.f;
        #pragma unroll 1
        for (int o = rpart; o < 49; o += 6) {
            const int dyi = o / 7;
            const int dxi = o - dyi * 7;
            float4 nv = N4[((rpR >> (4 * dyi)) & 15) * RS_ + ((cpR >> (4 * dxi)) & 15)];
            float4 qv = Q4[o];
            float a0 = qv.x - nv.x, a1 = qv.y - nv.y, a2 = qv.z - nv.z;
            t0 += a0 * a0; t1 += a1 * a1; t2 += a2 * a2;
        }
        partial = t0 + t1 + t2;
        // mask = (d0 / 147 < 0.5)  <=>  d0 < 73.5
        if (!(myD < 73.5f)) partial = 0.f;
    }
    // one 64-wide sum: sum_k mask_k * dref_k (order-free)
    #pragma unroll
    for (int off = 32; off >= 1; off >>= 1)
        partial += __shfl_xor(partial, off, 64);

    if (lane == 0)
        atomicAdd(&acc[wsid & (NSLOTS - 1)], partial * (1.0f / (float)TOTAL_SEL));
}

__global__ __launch_bounds__(64) void dnls_reduce(const float* __restrict__ acc,
                                                  float* __restrict__ out)
{
    const int lane = threadIdx.x;
    float v = 0.f;
    for (int i = lane; i < NSLOTS; i += 64) v += acc[i];
    #pragma unroll
    for (int off = 32; off >= 1; off >>= 1)
        v += __shfl_xor(v, off, 64);
    if (lane == 0) out[0] = v;
}

extern "C" void kernel_launch(void* const* d_in, const int* in_sizes, int n_in,
                              void* d_out, int out_size, void* d_ws, size_t ws_size,
                              hipStream_t stream) {
    const float* noisy = (const float*)d_in[0];
    const float* deno  = (const float*)d_in[2];
    const float* fflow = (const float*)d_in[3];
    const float* bflow = (const float*)d_in[4];
    float* out = (float*)d_out;
    float* acc = (float*)d_ws;

    hipMemsetAsync(acc, 0, NSLOTS * sizeof(float), stream);

    const int nblocks = (QN_ * 2) / 4;
    dnls_main<<<nblocks, 256, 0, stream>>>(noisy, deno, fflow, bflow, acc);
    dnls_reduce<<<1, 64, 0, stream>>>(acc, out);
}

// Round 6
// 586.573 us; speedup vs baseline: 5.5778x; 1.0698x over previous
//
#include <hip/hip_runtime.h>

#define T_ 5
#define C_ 3
#define H_ 128
#define W_ 128
#define HW_ (H_*W_)
#define WS_ 9
#define W2_ 81           // WS*WS
#define K_ 10
#define QN_ (T_*H_*W_)   // 81920
#define NSLOTS 1024
#define TOTAL_SEL (QN_ * 2 * K_)   // 1638400
#define R_ 15            // staged region side (window 9 + patch 7 - 1)
#define RS_ 17           // padded row stride in PIXELS (float4 each)

__device__ __forceinline__ int clampi(int v, int hi) {
    return v < 0 ? 0 : (v > hi ? hi : v);
}

// Packed per-patch-offset clamped LDS indices for window w (0..80).
// Honors the reference's DOUBLE clamp: row = clamp(clamp(cen+wy')+dy).
// Nibble j of rp/cp = clamped (row-rmin)/(col-cmin) for offset j-3, in [0,14].
__device__ __forceinline__ void mkpacks(int cen_y, int cen_x, int w, int rmin, int cmin,
                                        unsigned& rp, unsigned& cp) {
    const int by = clampi(cen_y + w / WS_ - 4, H_ - 1);
    const int bx = clampi(cen_x + w - (w / WS_) * WS_ - 4, W_ - 1);
    unsigned r = 0, c = 0;
    #pragma unroll
    for (int j = 0; j < 7; ++j) {
        r |= (unsigned)(clampi(by + j - 3, H_ - 1) - rmin) << (4 * j);
        c |= (unsigned)(clampi(bx + j - 3, W_ - 1) - cmin) << (4 * j);
    }
    rp = r; cp = c;
}

// One wave per (q, s). 4 waves / block.
// (256,8): 8 waves/SIMD -> VGPR cap 64; natural demand is ~52 (R5), no spills.
// LDS 19456 B/block -> 8 blocks/CU = 32 waves/CU (HW cap). The single region
// buffer sR is RESTAGED per wave: deno for search, then noisy for refine —
// halving LDS vs R5's dual-buffer was the occupancy lever.
__global__ __launch_bounds__(256, 8) void dnls_main(
    const float* __restrict__ noisy,
    const float* __restrict__ deno,
    const float* __restrict__ fflow,
    const float* __restrict__ bflow,
    float* __restrict__ acc)
{
    // channel-interleaved float4 (rgb+pad): 1 ds_read_b128 per pixel
    __shared__ float4 sR[4][R_ * RS_];   // region: deno@ct, later noisy@ct
    __shared__ float4 sQ[4][49];         // query patch (deno @ qt)

    const int wave = threadIdx.x >> 6;
    const int lane = threadIdx.x & 63;
    const int wsid = blockIdx.x * 4 + wave;
    const int q = wsid >> 1;
    const int s = wsid & 1;

    const int qt = q / HW_;
    const int qr = q - qt * HW_;
    const int qy = qr >> 7;
    const int qx = qr & 127;

    const int ct = (s == 0) ? (qt + 1 < T_ ? qt + 1 : T_ - 1)
                            : (qt - 1 > 0 ? qt - 1 : 0);

    const float* flow = (s == 0) ? fflow : bflow;
    const int fidx = (qt * 2 * H_ + qy) * W_ + qx;
    const int cen_x = qx + (int)rintf(flow[fidx]);
    const int cen_y = qy + (int)rintf(flow[fidx + HW_]);

    // ---- stage query patch (deno @ qt), interleaved ----
    if (lane < 49) {
        const int dy = lane / 7 - 3;
        const int dx = lane - (lane / 7) * 7 - 3;
        const int yy = clampi(qy + dy, H_ - 1);
        const int xx = clampi(qx + dx, W_ - 1);
        const float* p = deno + (size_t)qt * C_ * HW_ + yy * W_ + xx;
        sQ[wave][lane] = make_float4(p[0], p[HW_], p[2 * HW_], 0.f);
    }

    // ---- stage 15x15 candidate region (deno @ ct), interleaved ----
    const int rmin = clampi(cen_y - 7, H_ - 1);
    const int cmin = clampi(cen_x - 7, W_ - 1);
    const float* cfrm = deno  + (size_t)ct * C_ * HW_;
    const float* nfrm = noisy + (size_t)ct * C_ * HW_;
    // region geometry (same for both stagings)
    int gidx[4], lidx[4];
    {
        int n = 0;
        for (int i = lane; i < R_ * R_; i += 64, ++n) {
            const int ry = i / R_;
            const int rx = i - ry * R_;
            int sy = rmin + ry; if (sy > H_ - 1) sy = H_ - 1;
            int sx = cmin + rx; if (sx > W_ - 1) sx = W_ - 1;
            gidx[n] = sy * W_ + sx;
            lidx[n] = ry * RS_ + rx;
        }
        for (; n < 4; ++n) { gidx[n] = -1; lidx[n] = 0; }
    }
    #pragma unroll
    for (int n = 0; n < 4; ++n) {
        if (gidx[n] >= 0) {
            const int gi = gidx[n];
            sR[wave][lidx[n]] = make_float4(cfrm[gi], cfrm[HW_ + gi], cfrm[2 * HW_ + gi], 0.f);
        }
    }
    __syncthreads();

    const float4* C4 = &sR[wave][0];
    const float4* Q4 = &sQ[wave][0];

    // ---- pass 1: windows w = lane (0..63), full SSD per lane ----
    unsigned rp1, cp1;
    mkpacks(cen_y, cen_x, lane, rmin, cmin, rp1, cp1);
    float s0 = 0.f, s1 = 0.f, s2 = 0.f;
    #pragma unroll 1
    for (int dy = 0; dy < 7; ++dy) {
        const float4* Crow = C4 + ((rp1 >> (4 * dy)) & 15) * RS_;
        const float4* Qrow = Q4 + dy * 7;
        #pragma unroll 4
        for (int dx = 0; dx < 7; ++dx) {
            float4 cv = Crow[(cp1 >> (4 * dx)) & 15];
            float4 qv = Qrow[dx];
            float a0 = qv.x - cv.x, a1 = qv.y - cv.y, a2 = qv.z - cv.z;
            s0 += a0 * a0; s1 += a1 * a1; s2 += a2 * a2;
        }
    }
    const float d1 = s0 + s1 + s2;

    // ---- pass 2: windows 64..80, 3 lanes per window ----
    float d2 = 0.f;
    const int w2   = 64 + lane / 3;          // valid for lane < 51
    const int part = lane - (lane / 3) * 3;
    if (lane < 51) {
        unsigned rp2, cp2;
        mkpacks(cen_y, cen_x, w2, rmin, cmin, rp2, cp2);
        float t0 = 0.f, t1 = 0.f, t2 = 0.f;
        #pragma unroll 1
        for (int o = part; o < 49; o += 3) {
            const int dyi = o / 7;
            const int dxi = o - dyi * 7;
            float4 cv = C4[((rp2 >> (4 * dyi)) & 15) * RS_ + ((cp2 >> (4 * dxi)) & 15)];
            float4 qv = Q4[o];
            float a0 = qv.x - cv.x, a1 = qv.y - cv.y, a2 = qv.z - cv.z;
            t0 += a0 * a0; t1 += a1 * a1; t2 += a2 * a2;
        }
        d2 = t0 + t1 + t2;
    }
    const int base3 = lane * 3;
    float dd = __shfl(d2, base3 < 64 ? base3 : 0)
             + __shfl(d2, base3 + 1 < 64 ? base3 + 1 : 0)
             + __shfl(d2, base3 + 2 < 64 ? base3 + 2 : 0);

    // ---- restage region with noisy (refine source). Per-wave buffer: the
    // wave's own DS reads above complete before these writes (in-order DS
    // pipe); write latency hides under the register-only top-k below. ----
    #pragma unroll
    for (int n = 0; n < 4; ++n) {
        if (gidx[n] >= 0) {
            const int gi = gidx[n];
            sR[wave][lidx[n]] = make_float4(nfrm[gi], nfrm[HW_ + gi], nfrm[2 * HW_ + gi], 0.f);
        }
    }

    // ---- top-K with 32-bit keys: (dist_bits & ~0x7F) | w ----
    // Monotone floor-quantization (2^-16 relative), unique (w in low 7 bits),
    // exact ties -> lower w (matches lax.top_k).
    unsigned k0 = (__float_as_uint(d1) & 0xFFFFFF80u) | (unsigned)lane;
    unsigned k1 = (lane < 17)
        ? ((__float_as_uint(dd) & 0xFFFFFF80u) | (unsigned)(64 + lane))
        : 0xFFFFFFFFu;

    const int lane_mod10 = lane % 10;
    unsigned myKey = 0;

    for (int k = 0; k < K_; ++k) {
        unsigned m = (k0 < k1) ? k0 : k1;
        #pragma unroll
        for (int off = 32; off >= 1; off >>= 1) {
            unsigned o = __shfl_xor(m, off, 64);
            m = (o < m) ? o : m;
        }
        if (m == k0) k0 = 0xFFFFFFFFu;
        if (m == k1) k1 = 0xFFFFFFFFu;
        if (lane < 60 && lane_mod10 == k) myKey = m;
    }

    const int   myW = (int)(myKey & 0x7Fu);
    const float myD = __uint_as_float(myKey & 0xFFFFFF80u);

    __syncthreads();   // restage writes visible to all lanes of this wave

    // ---- refine: SSD(deno query, noisy candidate), mask applied per lane ----
    float partial = 0.f;
    if (lane < 60) {
        unsigned rpR, cpR;
        mkpacks(cen_y, cen_x, myW, rmin, cmin, rpR, cpR);
        const int rpart = lane / 10;   // 0..5
        float t0 = 0.f, t1 = 0.f, t2 = 0.f;
        #pragma unroll 1
        for (int o = rpart; o < 49; o += 6) {
            const int dyi = o / 7;
            const int dxi = o - dyi * 7;
            float4 nv = C4[((rpR >> (4 * dyi)) & 15) * RS_ + ((cpR >> (4 * dxi)) & 15)];
            float4 qv = Q4[o];
            float a0 = qv.x - nv.x, a1 = qv.y - nv.y, a2 = qv.z - nv.z;
            t0 += a0 * a0; t1 += a1 * a1; t2 += a2 * a2;
        }
        partial = t0 + t1 + t2;
        // mask = (d0 / 147 < 0.5)  <=>  d0 < 73.5
        if (!(myD < 73.5f)) partial = 0.f;
    }
    // one 64-wide sum: sum_k mask_k * dref_k (order-free)
    #pragma unroll
    for (int off = 32; off >= 1; off >>= 1)
        partial += __shfl_xor(partial, off, 64);

    if (lane == 0)
        atomicAdd(&acc[wsid & (NSLOTS - 1)], partial * (1.0f / (float)TOTAL_SEL));
}

__global__ __launch_bounds__(64) void dnls_reduce(const float* __restrict__ acc,
                                                  float* __restrict__ out)
{
    const int lane = threadIdx.x;
    float v = 0.f;
    for (int i = lane; i < NSLOTS; i += 64) v += acc[i];
    #pragma unroll
    for (int off = 32; off >= 1; off >>= 1)
        v += __shfl_xor(v, off, 64);
    if (lane == 0) out[0] = v;
}

extern "C" void kernel_launch(void* const* d_in, const int* in_sizes, int n_in,
                              void* d_out, int out_size, void* d_ws, size_t ws_size,
                              hipStream_t stream) {
    const float* noisy = (const float*)d_in[0];
    const float* deno  = (const float*)d_in[2];
    const float* fflow = (const float*)d_in[3];
    const float* bflow = (const float*)d_in[4];
    float* out = (float*)d_out;
    float* acc = (float*)d_ws;

    hipMemsetAsync(acc, 0, NSLOTS * sizeof(float), stream);

    const int nblocks = (QN_ * 2) / 4;
    dnls_main<<<nblocks, 256, 0, stream>>>(noisy, deno, fflow, bflow, acc);
    dnls_reduce<<<1, 64, 0, stream>>>(acc, out);
}

// Round 7
// 546.361 us; speedup vs baseline: 5.9883x; 1.0736x over previous
//
#include <hip/hip_runtime.h>

#define T_ 5
#define C_ 3
#define H_ 128
#define W_ 128
#define HW_ (H_*W_)
#define WS_ 9
#define W2_ 81           // WS*WS
#define K_ 10
#define QN_ (T_*H_*W_)   // 81920
#define NSLOTS 1024
#define TOTAL_SEL (QN_ * 2 * K_)   // 1638400
#define R_ 15            // staged region side (window 9 + patch 7 - 1)
#define RS_ 17           // padded row stride in PIXELS (float4 each)
#define RRS_ (R_*RS_)    // 255 float4 per region

__device__ __forceinline__ int clampi(int v, int hi) {
    return v < 0 ? 0 : (v > hi ? hi : v);
}

// Packed per-patch-offset clamped LDS indices for window w (0..80).
// Honors the reference's DOUBLE clamp: row = clamp(clamp(cen+wy')+dy).
// Nibble j of rp/cp = clamped (row-rmin)/(col-cmin) for offset j-3, in [0,14].
__device__ __forceinline__ void mkpacks(int cen_y, int cen_x, int w, int rmin, int cmin,
                                        unsigned& rp, unsigned& cp) {
    const int by = clampi(cen_y + w / WS_ - 4, H_ - 1);
    const int bx = clampi(cen_x + w - (w / WS_) * WS_ - 4, W_ - 1);
    unsigned r = 0, c = 0;
    #pragma unroll
    for (int j = 0; j < 7; ++j) {
        r |= (unsigned)(clampi(by + j - 3, H_ - 1) - rmin) << (4 * j);
        c |= (unsigned)(clampi(bx + j - 3, W_ - 1) - cmin) << (4 * j);
    }
    rp = r; cp = c;
}

// ONE WAVE PER QUERY q, both directions s=0,1 fused: the query-pixel LDS
// read is shared between directions (pass1: 147 reads vs 196 split). LDS pipe
// is the measured bottleneck (R6: ~2300 LDS cyc/wave x 640 waves/CU ~= total
// kernel cycles), so wave-instruction count is the currency.
__global__ __launch_bounds__(256, 4) void dnls_main(
    const float* __restrict__ noisy,
    const float* __restrict__ deno,
    const float* __restrict__ fflow,
    const float* __restrict__ bflow,
    float* __restrict__ acc)
{
    // channel-interleaved float4 (rgb+pad): 1 ds_read_b128 per pixel
    __shared__ float4 sR[4][2 * RRS_];   // regions s0|s1: deno@ct, later noisy@ct
    __shared__ float4 sQ[4][49];         // query patch (deno @ qt)

    const int wave = threadIdx.x >> 6;
    const int lane = threadIdx.x & 63;
    const int q = blockIdx.x * 4 + wave;

    const int qt = q / HW_;
    const int qr = q - qt * HW_;
    const int qy = qr >> 7;
    const int qx = qr & 127;

    const int ct0 = (qt + 1 < T_) ? qt + 1 : T_ - 1;
    const int ct1 = (qt - 1 > 0) ? qt - 1 : 0;

    const int fidx = (qt * 2 * H_ + qy) * W_ + qx;
    const int cen_x0 = qx + (int)rintf(fflow[fidx]);
    const int cen_y0 = qy + (int)rintf(fflow[fidx + HW_]);
    const int cen_x1 = qx + (int)rintf(bflow[fidx]);
    const int cen_y1 = qy + (int)rintf(bflow[fidx + HW_]);

    // ---- stage query patch (deno @ qt), interleaved ----
    if (lane < 49) {
        const int dy = lane / 7 - 3;
        const int dx = lane - (lane / 7) * 7 - 3;
        const int yy = clampi(qy + dy, H_ - 1);
        const int xx = clampi(qx + dx, W_ - 1);
        const float* p = deno + (size_t)qt * C_ * HW_ + yy * W_ + xx;
        sQ[wave][lane] = make_float4(p[0], p[HW_], p[2 * HW_], 0.f);
    }

    // ---- stage both 15x15 regions (deno @ ct0 / ct1) ----
    const int rmin0 = clampi(cen_y0 - 7, H_ - 1);
    const int cmin0 = clampi(cen_x0 - 7, W_ - 1);
    const int rmin1 = clampi(cen_y1 - 7, H_ - 1);
    const int cmin1 = clampi(cen_x1 - 7, W_ - 1);
    const float* cfrm0 = deno  + (size_t)ct0 * C_ * HW_;
    const float* cfrm1 = deno  + (size_t)ct1 * C_ * HW_;
    const float* nfrm0 = noisy + (size_t)ct0 * C_ * HW_;
    const float* nfrm1 = noisy + (size_t)ct1 * C_ * HW_;

    int gidx[8], lidx[8];   // cached geometry for the later noisy restage
    {
        int n = 0;
        for (int i = lane; i < 2 * R_ * R_; i += 64, ++n) {
            const int reg = (i >= R_ * R_);
            const int rem = i - reg * (R_ * R_);
            const int ry = rem / R_;
            const int rx = rem - ry * R_;
            int sy = (reg ? rmin1 : rmin0) + ry; if (sy > H_ - 1) sy = H_ - 1;
            int sx = (reg ? cmin1 : cmin0) + rx; if (sx > W_ - 1) sx = W_ - 1;
            gidx[n] = sy * W_ + sx;
            lidx[n] = reg * RRS_ + ry * RS_ + rx;
        }
        for (; n < 8; ++n) { gidx[n] = -1; lidx[n] = 0; }
    }
    #pragma unroll
    for (int n = 0; n < 8; ++n) {
        if (gidx[n] >= 0) {
            const float* f = (lidx[n] >= RRS_) ? cfrm1 : cfrm0;
            const int gi = gidx[n];
            sR[wave][lidx[n]] = make_float4(f[gi], f[HW_ + gi], f[2 * HW_ + gi], 0.f);
        }
    }
    __syncthreads();

    const float4* R0 = &sR[wave][0];
    const float4* R1 = &sR[wave][RRS_];
    const float4* Q4 = &sQ[wave][0];

    // ---- pass 1: window w = lane (0..63), BOTH directions per iteration ----
    unsigned rpA, cpA, rpB, cpB;
    mkpacks(cen_y0, cen_x0, lane, rmin0, cmin0, rpA, cpA);
    mkpacks(cen_y1, cen_x1, lane, rmin1, cmin1, rpB, cpB);
    float u0 = 0.f, u1 = 0.f, u2 = 0.f;   // s0 accum (per channel)
    float v0 = 0.f, v1 = 0.f, v2 = 0.f;   // s1 accum
    #pragma unroll 1
    for (int dy = 0; dy < 7; ++dy) {
        const float4* CrowA = R0 + ((rpA >> (4 * dy)) & 15) * RS_;
        const float4* CrowB = R1 + ((rpB >> (4 * dy)) & 15) * RS_;
        const float4* Qrow = Q4 + dy * 7;
        #pragma unroll 4
        for (int dx = 0; dx < 7; ++dx) {
            float4 qv = Qrow[dx];
            float4 ca = CrowA[(cpA >> (4 * dx)) & 15];
            float4 cb = CrowB[(cpB >> (4 * dx)) & 15];
            float a0 = qv.x - ca.x, a1 = qv.y - ca.y, a2 = qv.z - ca.z;
            float b0 = qv.x - cb.x, b1 = qv.y - cb.y, b2 = qv.z - cb.z;
            u0 += a0 * a0; u1 += a1 * a1; u2 += a2 * a2;
            v0 += b0 * b0; v1 += b1 * b1; v2 += b2 * b2;
        }
    }
    const float d1_0 = u0 + u1 + u2;
    const float d1_1 = v0 + v1 + v2;

    // ---- pass 2: windows 64..80, 3 lanes per window, both directions ----
    float d2_0 = 0.f, d2_1 = 0.f;
    const int w2   = 64 + lane / 3;          // valid for lane < 51
    const int part = lane - (lane / 3) * 3;
    if (lane < 51) {
        unsigned rp2A, cp2A, rp2B, cp2B;
        mkpacks(cen_y0, cen_x0, w2, rmin0, cmin0, rp2A, cp2A);
        mkpacks(cen_y1, cen_x1, w2, rmin1, cmin1, rp2B, cp2B);
        float t0 = 0.f, t1 = 0.f, t2 = 0.f;
        float w0 = 0.f, w1 = 0.f, w2a = 0.f;
        #pragma unroll 1
        for (int o = part; o < 49; o += 3) {
            const int dyi = o / 7;
            const int dxi = o - dyi * 7;
            float4 qv = Q4[o];
            float4 ca = R0[((rp2A >> (4 * dyi)) & 15) * RS_ + ((cp2A >> (4 * dxi)) & 15)];
            float4 cb = R1[((rp2B >> (4 * dyi)) & 15) * RS_ + ((cp2B >> (4 * dxi)) & 15)];
            float a0 = qv.x - ca.x, a1 = qv.y - ca.y, a2 = qv.z - ca.z;
            float b0 = qv.x - cb.x, b1 = qv.y - cb.y, b2 = qv.z - cb.z;
            t0 += a0 * a0; t1 += a1 * a1; t2 += a2 * a2;
            w0 += b0 * b0; w1 += b1 * b1; w2a += b2 * b2;
        }
        d2_0 = t0 + t1 + t2;
        d2_1 = w0 + w1 + w2a;
    }
    const int base3 = lane * 3;
    const int g0 = base3 < 64 ? base3 : 0;
    const int g1 = base3 + 1 < 64 ? base3 + 1 : 0;
    const int g2 = base3 + 2 < 64 ? base3 + 2 : 0;
    float dd0 = __shfl(d2_0, g0) + __shfl(d2_0, g1) + __shfl(d2_0, g2);
    float dd1 = __shfl(d2_1, g0) + __shfl(d2_1, g1) + __shfl(d2_1, g2);

    // ---- restage both regions with noisy (refine source). Per-wave buffer:
    // this wave's deno reads are done; write latency hides under top-k. ----
    #pragma unroll
    for (int n = 0; n < 8; ++n) {
        if (gidx[n] >= 0) {
            const float* f = (lidx[n] >= RRS_) ? nfrm1 : nfrm0;
            const int gi = gidx[n];
            sR[wave][lidx[n]] = make_float4(f[gi], f[HW_ + gi], f[2 * HW_ + gi], 0.f);
        }
    }

    // ---- two top-10s with 32-bit keys: (dist_bits & ~0x7F) | w ----
    // Monotone floor-quantization, unique (w in low 7 bits), exact ties ->
    // lower w (matches lax.top_k). Refine layout: lane<60: sel=lane%20
    // (0..9 = s0 picks, 10..19 = s1 picks), part=lane/20 (0..2).
    const int sel = lane % 20;
    unsigned myKey = 0;

    {   // s0
        unsigned k0 = (__float_as_uint(d1_0) & 0xFFFFFF80u) | (unsigned)lane;
        unsigned k1 = (lane < 17)
            ? ((__float_as_uint(dd0) & 0xFFFFFF80u) | (unsigned)(64 + lane))
            : 0xFFFFFFFFu;
        for (int k = 0; k < K_; ++k) {
            unsigned m = (k0 < k1) ? k0 : k1;
            #pragma unroll
            for (int off = 32; off >= 1; off >>= 1) {
                unsigned o = __shfl_xor(m, off, 64);
                m = (o < m) ? o : m;
            }
            if (m == k0) k0 = 0xFFFFFFFFu;
            if (m == k1) k1 = 0xFFFFFFFFu;
            if (lane < 60 && sel == k) myKey = m;
        }
    }
    {   // s1
        unsigned k0 = (__float_as_uint(d1_1) & 0xFFFFFF80u) | (unsigned)lane;
        unsigned k1 = (lane < 17)
            ? ((__float_as_uint(dd1) & 0xFFFFFF80u) | (unsigned)(64 + lane))
            : 0xFFFFFFFFu;
        for (int k = 0; k < K_; ++k) {
            unsigned m = (k0 < k1) ? k0 : k1;
            #pragma unroll
            for (int off = 32; off >= 1; off >>= 1) {
                unsigned o = __shfl_xor(m, off, 64);
                m = (o < m) ? o : m;
            }
            if (m == k0) k0 = 0xFFFFFFFFu;
            if (m == k1) k1 = 0xFFFFFFFFu;
            if (lane < 60 && sel == 10 + k) myKey = m;
        }
    }

    const int   myW = (int)(myKey & 0x7Fu);
    const float myD = __uint_as_float(myKey & 0xFFFFFF80u);

    __syncthreads();   // restage writes drained

    // ---- refine: SSD(deno query, noisy candidate), mask applied per lane ----
    float partial = 0.f;
    if (lane < 60) {
        const int s1sel = (sel >= 10);
        const int ceny = s1sel ? cen_y1 : cen_y0;
        const int cenx = s1sel ? cen_x1 : cen_x0;
        const int rmr  = s1sel ? rmin1 : rmin0;
        const int cmr  = s1sel ? cmin1 : cmin0;
        const float4* Nb = s1sel ? R1 : R0;
        unsigned rpR, cpR;
        mkpacks(ceny, cenx, myW, rmr, cmr, rpR, cpR);
        const int rpart = lane / 20;   // 0..2
        float t0 = 0.f, t1 = 0.f, t2 = 0.f;
        #pragma unroll 1
        for (int o = rpart; o < 49; o += 3) {
            const int dyi = o / 7;
            const int dxi = o - dyi * 7;
            float4 nv = Nb[((rpR >> (4 * dyi)) & 15) * RS_ + ((cpR >> (4 * dxi)) & 15)];
            float4 qv = Q4[o];
            float a0 = qv.x - nv.x, a1 = qv.y - nv.y, a2 = qv.z - nv.z;
            t0 += a0 * a0; t1 += a1 * a1; t2 += a2 * a2;
        }
        partial = t0 + t1 + t2;
        // mask = (d0 / 147 < 0.5)  <=>  d0 < 73.5
        if (!(myD < 73.5f)) partial = 0.f;
    }
    // one 64-wide sum over all 20 selections' partials (order-free)
    #pragma unroll
    for (int off = 32; off >= 1; off >>= 1)
        partial += __shfl_xor(partial, off, 64);

    if (lane == 0)
        atomicAdd(&acc[q & (NSLOTS - 1)], partial * (1.0f / (float)TOTAL_SEL));
}

__global__ __launch_bounds__(64) void dnls_reduce(const float* __restrict__ acc,
                                                  float* __restrict__ out)
{
    const int lane = threadIdx.x;
    float v = 0.f;
    for (int i = lane; i < NSLOTS; i += 64) v += acc[i];
    #pragma unroll
    for (int off = 32; off >= 1; off >>= 1)
        v += __shfl_xor(v, off, 64);
    if (lane == 0) out[0] = v;
}

extern "C" void kernel_launch(void* const* d_in, const int* in_sizes, int n_in,
                              void* d_out, int out_size, void* d_ws, size_t ws_size,
                              hipStream_t stream) {
    const float* noisy = (const float*)d_in[0];
    const float* deno  = (const float*)d_in[2];
    const float* fflow = (const float*)d_in[3];
    const float* bflow = (const float*)d_in[4];
    float* out = (float*)d_out;
    float* acc = (float*)d_ws;

    hipMemsetAsync(acc, 0, NSLOTS * sizeof(float), stream);

    const int nblocks = QN_ / 4;   // one wave per query, 4 waves/block
    dnls_main<<<nblocks, 256, 0, stream>>>(noisy, deno, fflow, bflow, acc);
    dnls_reduce<<<1, 64, 0, stream>>>(acc, out);
}

// Round 8
// 473.344 us; speedup vs baseline: 6.9120x; 1.1543x over previous
//
#include <hip/hip_runtime.h>

#define T_ 5
#define C_ 3
#define H_ 128
#define W_ 128
#define HW_ (H_*W_)
#define WS_ 9
#define W2_ 81           // WS*WS
#define K_ 10
#define QN_ (T_*H_*W_)   // 81920
#define NSLOTS 1024
#define TOTAL_SEL (QN_ * 2 * K_)   // 1638400
#define R_ 15            // staged region side (window 9 + patch 7 - 1)
#define RS_ 17           // padded row stride in PIXELS (float4 each)
#define RRS_ (R_*RS_)    // 255 float4 per region

__device__ __forceinline__ int clampi(int v, int hi) {
    return v < 0 ? 0 : (v > hi ? hi : v);
}

__device__ __forceinline__ float readlane_f(float v, int l) {
    return __uint_as_float(__builtin_amdgcn_readlane(__float_as_uint(v), l));
}

__device__ __forceinline__ int mbcnt64(unsigned long long m) {
    return __builtin_amdgcn_mbcnt_hi((unsigned)(m >> 32),
           __builtin_amdgcn_mbcnt_lo((unsigned)m, 0));
}

// Packed per-patch-offset clamped LDS indices for window w (0..80).
// Honors the reference's DOUBLE clamp: row = clamp(clamp(cen+wy')+dy).
__device__ __forceinline__ void mkpacks(int cen_y, int cen_x, int w, int rmin, int cmin,
                                        unsigned& rp, unsigned& cp) {
    const int by = clampi(cen_y + w / WS_ - 4, H_ - 1);
    const int bx = clampi(cen_x + w - (w / WS_) * WS_ - 4, W_ - 1);
    unsigned r = 0, c = 0;
    #pragma unroll
    for (int j = 0; j < 7; ++j) {
        r |= (unsigned)(clampi(by + j - 3, H_ - 1) - rmin) << (4 * j);
        c |= (unsigned)(clampi(bx + j - 3, W_ - 1) - cmin) << (4 * j);
    }
    rp = r; cp = c;
}

// One wave per query q, both directions fused. All LDS traffic is WAVE-
// PRIVATE; per-wave DS ops execute in order -> no __syncthreads anywhere.
// LDS pipe is the measured bottleneck (R7: ~3700 LDS cyc/wave ~= kernel
// cycles at 320 waves/CU); this round moves Q-reads to v_readlane (VALU)
// and the top-k to ballot/bitwise rank-select (VALU/SALU).
__global__ __launch_bounds__(256, 4) void dnls_main(
    const float* __restrict__ noisy,
    const float* __restrict__ deno,
    const float* __restrict__ fflow,
    const float* __restrict__ bflow,
    float* __restrict__ acc)
{
    __shared__ float4 sR[4][2 * RRS_];   // regions s0|s1: deno@ct, later noisy@ct
    __shared__ float4 sQ[4][49];         // query patch (for pass2/refine's varying o)
    __shared__ unsigned sSlot[4][20];    // compacted top-k keys

    const int wave = threadIdx.x >> 6;
    const int lane = threadIdx.x & 63;
    const int q = blockIdx.x * 4 + wave;

    const int qt = q / HW_;
    const int qr = q - qt * HW_;
    const int qy = qr >> 7;
    const int qx = qr & 127;

    const int ct0 = (qt + 1 < T_) ? qt + 1 : T_ - 1;
    const int ct1 = (qt - 1 > 0) ? qt - 1 : 0;

    const int fidx = (qt * 2 * H_ + qy) * W_ + qx;
    const int cen_x0 = qx + (int)rintf(fflow[fidx]);
    const int cen_y0 = qy + (int)rintf(fflow[fidx + HW_]);
    const int cen_x1 = qx + (int)rintf(bflow[fidx]);
    const int cen_y1 = qy + (int)rintf(bflow[fidx + HW_]);

    // ---- stage query patch: registers (lane o<49 holds pixel o) + LDS copy ----
    float4 qreg = make_float4(0.f, 0.f, 0.f, 0.f);
    if (lane < 49) {
        const int dy = lane / 7 - 3;
        const int dx = lane - (lane / 7) * 7 - 3;
        const int yy = clampi(qy + dy, H_ - 1);
        const int xx = clampi(qx + dx, W_ - 1);
        const float* p = deno + (size_t)qt * C_ * HW_ + yy * W_ + xx;
        qreg = make_float4(p[0], p[HW_], p[2 * HW_], 0.f);
        sQ[wave][lane] = qreg;
    }

    // ---- stage both 15x15 regions (deno @ ct0/ct1), wave-private ----
    const int rmin0 = clampi(cen_y0 - 7, H_ - 1);
    const int cmin0 = clampi(cen_x0 - 7, W_ - 1);
    const int rmin1 = clampi(cen_y1 - 7, H_ - 1);
    const int cmin1 = clampi(cen_x1 - 7, W_ - 1);
    const float* cfrm0 = deno  + (size_t)ct0 * C_ * HW_;
    const float* cfrm1 = deno  + (size_t)ct1 * C_ * HW_;
    const float* nfrm0 = noisy + (size_t)ct0 * C_ * HW_;
    const float* nfrm1 = noisy + (size_t)ct1 * C_ * HW_;

    int gidx[8], lidx[8];
    {
        int n = 0;
        for (int i = lane; i < 2 * R_ * R_; i += 64, ++n) {
            const int reg = (i >= R_ * R_);
            const int rem = i - reg * (R_ * R_);
            const int ry = rem / R_;
            const int rx = rem - ry * R_;
            int sy = (reg ? rmin1 : rmin0) + ry; if (sy > H_ - 1) sy = H_ - 1;
            int sx = (reg ? cmin1 : cmin0) + rx; if (sx > W_ - 1) sx = W_ - 1;
            gidx[n] = sy * W_ + sx;
            lidx[n] = reg * RRS_ + ry * RS_ + rx;
        }
        for (; n < 8; ++n) { gidx[n] = -1; lidx[n] = 0; }
    }
    #pragma unroll
    for (int n = 0; n < 8; ++n) {
        if (gidx[n] >= 0) {
            const float* f = (lidx[n] >= RRS_) ? cfrm1 : cfrm0;
            const int gi = gidx[n];
            sR[wave][lidx[n]] = make_float4(f[gi], f[HW_ + gi], f[2 * HW_ + gi], 0.f);
        }
    }

    const float4* R0 = &sR[wave][0];
    const float4* R1 = &sR[wave][RRS_];
    const float4* Q4 = &sQ[wave][0];

    // ---- pass 1: window w = lane, both directions; Q via v_readlane ----
    unsigned rpA, cpA, rpB, cpB;
    mkpacks(cen_y0, cen_x0, lane, rmin0, cmin0, rpA, cpA);
    mkpacks(cen_y1, cen_x1, lane, rmin1, cmin1, rpB, cpB);
    float u0 = 0.f, u1 = 0.f, u2 = 0.f;
    float v0 = 0.f, v1 = 0.f, v2 = 0.f;
    #pragma unroll 1
    for (int dy = 0; dy < 7; ++dy) {
        const float4* CrowA = R0 + ((rpA >> (4 * dy)) & 15) * RS_;
        const float4* CrowB = R1 + ((rpB >> (4 * dy)) & 15) * RS_;
        const int ob = dy * 7;
        #pragma unroll 4
        for (int dx = 0; dx < 7; ++dx) {
            const float qvx = readlane_f(qreg.x, ob + dx);
            const float qvy = readlane_f(qreg.y, ob + dx);
            const float qvz = readlane_f(qreg.z, ob + dx);
            float4 ca = CrowA[(cpA >> (4 * dx)) & 15];
            float4 cb = CrowB[(cpB >> (4 * dx)) & 15];
            float a0 = qvx - ca.x, a1 = qvy - ca.y, a2 = qvz - ca.z;
            float b0 = qvx - cb.x, b1 = qvy - cb.y, b2 = qvz - cb.z;
            u0 += a0 * a0; u1 += a1 * a1; u2 += a2 * a2;
            v0 += b0 * b0; v1 += b1 * b1; v2 += b2 * b2;
        }
    }
    const float d1_0 = u0 + u1 + u2;
    const float d1_1 = v0 + v1 + v2;

    // ---- pass 2: windows 64..80, 3 lanes per window, both directions ----
    float d2_0 = 0.f, d2_1 = 0.f;
    const int w2   = 64 + lane / 3;          // valid for lane < 51
    const int part = lane - (lane / 3) * 3;
    if (lane < 51) {
        unsigned rp2A, cp2A, rp2B, cp2B;
        mkpacks(cen_y0, cen_x0, w2, rmin0, cmin0, rp2A, cp2A);
        mkpacks(cen_y1, cen_x1, w2, rmin1, cmin1, rp2B, cp2B);
        float t0 = 0.f, t1 = 0.f, t2 = 0.f;
        float w0 = 0.f, w1 = 0.f, w2a = 0.f;
        #pragma unroll 1
        for (int o = part; o < 49; o += 3) {
            const int dyi = o / 7;
            const int dxi = o - dyi * 7;
            float4 qv = Q4[o];
            float4 ca = R0[((rp2A >> (4 * dyi)) & 15) * RS_ + ((cp2A >> (4 * dxi)) & 15)];
            float4 cb = R1[((rp2B >> (4 * dyi)) & 15) * RS_ + ((cp2B >> (4 * dxi)) & 15)];
            float a0 = qv.x - ca.x, a1 = qv.y - ca.y, a2 = qv.z - ca.z;
            float b0 = qv.x - cb.x, b1 = qv.y - cb.y, b2 = qv.z - cb.z;
            t0 += a0 * a0; t1 += a1 * a1; t2 += a2 * a2;
            w0 += b0 * b0; w1 += b1 * b1; w2a += b2 * b2;
        }
        d2_0 = t0 + t1 + t2;
        d2_1 = w0 + w1 + w2a;
    }
    const int base3 = lane * 3;
    const int g0 = base3 < 64 ? base3 : 0;
    const int g1 = base3 + 1 < 64 ? base3 + 1 : 0;
    const int g2 = base3 + 2 < 64 ? base3 + 2 : 0;
    float dd0 = __shfl(d2_0, g0) + __shfl(d2_0, g1) + __shfl(d2_0, g2);
    float dd1 = __shfl(d2_1, g0) + __shfl(d2_1, g1) + __shfl(d2_1, g2);

    // ---- restage both regions with noisy; wave-private, in-order DS ----
    #pragma unroll
    for (int n = 0; n < 8; ++n) {
        if (gidx[n] >= 0) {
            const float* f = (lidx[n] >= RRS_) ? nfrm1 : nfrm0;
            const int gi = gidx[n];
            sR[wave][lidx[n]] = make_float4(f[gi], f[HW_ + gi], f[2 * HW_ + gi], 0.f);
        }
    }

    // ---- top-10 per direction via bitwise rank-select (no LDS pipe) ----
    // keys: (dist_bits & ~0x7F) | w — monotone, unique, exact ties -> lower w
    // (matches lax.top_k). tau = rank-9 key; selected = keys <= tau.
    const unsigned kA0 = (__float_as_uint(d1_0) & 0xFFFFFF80u) | (unsigned)lane;
    const unsigned kA1 = (__float_as_uint(d1_1) & 0xFFFFFF80u) | (unsigned)lane;
    const unsigned kB0 = (lane < 17)
        ? ((__float_as_uint(dd0) & 0xFFFFFF80u) | (unsigned)(64 + lane)) : 0xFFFFFFFFu;
    const unsigned kB1 = (lane < 17)
        ? ((__float_as_uint(dd1) & 0xFFFFFF80u) | (unsigned)(64 + lane)) : 0xFFFFFFFFu;

    unsigned tau0 = 0, tau1 = 0;
    #pragma unroll
    for (int b = 30; b >= 0; --b) {   // bit 31 (sign) always 0
        const unsigned t0v = tau0 | (1u << b);
        const unsigned t1v = tau1 | (1u << b);
        const int c0 = __popcll(__ballot(kA0 < t0v)) + __popcll(__ballot(kB0 < t0v));
        const int c1 = __popcll(__ballot(kA1 < t1v)) + __popcll(__ballot(kB1 < t1v));
        if (c0 <= 9) tau0 = t0v;
        if (c1 <= 9) tau1 = t1v;
    }

    // compact the 10 winners per direction into slots (any order is valid:
    // the masked refine sum is permutation-invariant)
    {
        const bool sA0 = (kA0 <= tau0), sB0 = (kB0 <= tau0);
        const unsigned long long mA0 = __ballot(sA0), mB0 = __ballot(sB0);
        if (sA0) sSlot[wave][mbcnt64(mA0)] = kA0;
        if (sB0) sSlot[wave][__popcll(mA0) + mbcnt64(mB0)] = kB0;
        const bool sA1 = (kA1 <= tau1), sB1 = (kB1 <= tau1);
        const unsigned long long mA1 = __ballot(sA1), mB1 = __ballot(sB1);
        if (sA1) sSlot[wave][10 + mbcnt64(mA1)] = kA1;
        if (sB1) sSlot[wave][10 + __popcll(mA1) + mbcnt64(mB1)] = kB1;
    }

    const int sel = lane % 20;
    const unsigned myKey = sSlot[wave][sel];   // in-order DS: writes above done
    const int   myW = (int)(myKey & 0x7Fu);
    const float myD = __uint_as_float(myKey & 0xFFFFFF80u);

    // ---- refine: SSD(deno query, noisy candidate), mask applied per lane ----
    float partial = 0.f;
    if (lane < 60) {
        const int s1sel = (sel >= 10);
        const int ceny = s1sel ? cen_y1 : cen_y0;
        const int cenx = s1sel ? cen_x1 : cen_x0;
        const int rmr  = s1sel ? rmin1 : rmin0;
        const int cmr  = s1sel ? cmin1 : cmin0;
        const float4* Nb = s1sel ? R1 : R0;
        unsigned rpR, cpR;
        mkpacks(ceny, cenx, myW, rmr, cmr, rpR, cpR);
        const int rpart = lane / 20;   // 0..2
        float t0 = 0.f, t1 = 0.f, t2 = 0.f;
        #pragma unroll 1
        for (int o = rpart; o < 49; o += 3) {
            const int dyi = o / 7;
            const int dxi = o - dyi * 7;
            float4 nv = Nb[((rpR >> (4 * dyi)) & 15) * RS_ + ((cpR >> (4 * dxi)) & 15)];
            float4 qv = Q4[o];
            float a0 = qv.x - nv.x, a1 = qv.y - nv.y, a2 = qv.z - nv.z;
            t0 += a0 * a0; t1 += a1 * a1; t2 += a2 * a2;
        }
        partial = t0 + t1 + t2;
        // mask = (d0 / 147 < 0.5)  <=>  d0 < 73.5
        if (!(myD < 73.5f)) partial = 0.f;
    }
    #pragma unroll
    for (int off = 32; off >= 1; off >>= 1)
        partial += __shfl_xor(partial, off, 64);

    if (lane == 0)
        atomicAdd(&acc[q & (NSLOTS - 1)], partial * (1.0f / (float)TOTAL_SEL));
}

__global__ __launch_bounds__(64) void dnls_reduce(const float* __restrict__ acc,
                                                  float* __restrict__ out)
{
    const int lane = threadIdx.x;
    float v = 0.f;
    for (int i = lane; i < NSLOTS; i += 64) v += acc[i];
    #pragma unroll
    for (int off = 32; off >= 1; off >>= 1)
        v += __shfl_xor(v, off, 64);
    if (lane == 0) out[0] = v;
}

extern "C" void kernel_launch(void* const* d_in, const int* in_sizes, int n_in,
                              void* d_out, int out_size, void* d_ws, size_t ws_size,
                              hipStream_t stream) {
    const float* noisy = (const float*)d_in[0];
    const float* deno  = (const float*)d_in[2];
    const float* fflow = (const float*)d_in[3];
    const float* bflow = (const float*)d_in[4];
    float* out = (float*)d_out;
    float* acc = (float*)d_ws;

    hipMemsetAsync(acc, 0, NSLOTS * sizeof(float), stream);

    const int nblocks = QN_ / 4;   // one wave per query, 4 waves/block
    dnls_main<<<nblocks, 256, 0, stream>>>(noisy, deno, fflow, bflow, acc);
    dnls_reduce<<<1, 64, 0, stream>>>(acc, out);
}

// Round 9
// 462.513 us; speedup vs baseline: 7.0739x; 1.0234x over previous
//
#include <hip/hip_runtime.h>

#define T_ 5
#define C_ 3
#define H_ 128
#define W_ 128
#define HW_ (H_*W_)
#define WS_ 9
#define K_ 10
#define QN_ (T_*H_*W_)   // 81920
#define NSLOTS 1024
#define TOTAL_SEL (QN_ * 2 * K_)   // 1638400
#define R_ 15            // staged region side (window 9 + patch 7 - 1)
#define RS_ 17           // padded row stride in PIXELS (float4 each)
#define RRS_ (R_*RS_)    // 255 float4 per region

__device__ __forceinline__ int clampi(int v, int hi) {
    return v < 0 ? 0 : (v > hi ? hi : v);
}
__device__ __forceinline__ float readlane_f(float v, int l) {
    return __uint_as_float(__builtin_amdgcn_readlane(__float_as_uint(v), l));
}
__device__ __forceinline__ int mbcnt64(unsigned long long m) {
    return __builtin_amdgcn_mbcnt_hi((unsigned)(m >> 32),
           __builtin_amdgcn_mbcnt_lo((unsigned)m, 0));
}

// Border (slow) pack: nibble j = clamp(clamp(cen+w4-4)+j-3) - mn  (double clamp)
__device__ __forceinline__ unsigned mkpack_axis(int cen, int w4, int mn) {
    const int b = clampi(cen + w4 - 4, H_ - 1);
    unsigned r = 0;
    #pragma unroll
    for (int j = 0; j < 7; ++j)
        r |= (unsigned)(clampi(b + j - 3, H_ - 1) - mn) << (4 * j);
    return r;
}
// Interior fast pack (no clamp can fire when 7 <= cen <= 120): nibble j = w4+j
__device__ __forceinline__ unsigned mkpack_int(int w4) {
    return (unsigned)w4 * 0x1111111u + 0x6543210u;
}

// One wave per query q, both directions fused; all LDS traffic wave-private
// (no __syncthreads). R8 post-mortem: VALU issue 100% saturated, LDS ~75%.
// R9: SSD via sumsq-in-.w decomposition (4 VALU/px/dir instead of 6),
// interior fast-path packs, hoisted pass-1 column offsets.
__global__ __launch_bounds__(256, 4) void dnls_main(
    const float* __restrict__ noisy,
    const float* __restrict__ deno,
    const float* __restrict__ fflow,
    const float* __restrict__ bflow,
    float* __restrict__ acc)
{
    __shared__ float4 sR[4][2 * RRS_];   // regions s0|s1: (rgb, sumsq); deno then noisy
    __shared__ float4 sQ[4][49];         // query patch as (-2q, 0)
    __shared__ unsigned sSlot[4][20];    // compacted top-k keys

    const int wave = threadIdx.x >> 6;
    const int lane = threadIdx.x & 63;
    const int q = blockIdx.x * 4 + wave;

    const int qt = q / HW_;
    const int qr = q - qt * HW_;
    const int qy = qr >> 7;
    const int qx = qr & 127;

    const int ct0 = (qt + 1 < T_) ? qt + 1 : T_ - 1;
    const int ct1 = (qt - 1 > 0) ? qt - 1 : 0;

    const int fidx = (qt * 2 * H_ + qy) * W_ + qx;
    const int cen_x0 = qx + (int)rintf(fflow[fidx]);
    const int cen_y0 = qy + (int)rintf(fflow[fidx + HW_]);
    const int cen_x1 = qx + (int)rintf(bflow[fidx]);
    const int cen_y1 = qy + (int)rintf(bflow[fidx + HW_]);

    // wave-uniform interior flags (no clamping possible anywhere in the axis)
    const bool iy0 = (cen_y0 >= 7) && (cen_y0 <= H_ - 8);
    const bool ix0 = (cen_x0 >= 7) && (cen_x0 <= W_ - 8);
    const bool iy1 = (cen_y1 >= 7) && (cen_y1 <= H_ - 8);
    const bool ix1 = (cen_x1 >= 7) && (cen_x1 <= W_ - 8);

    // ---- query patch: lane o<49 holds (-2q); qss = sum q^2 (uniform) ----
    float4 qreg = make_float4(0.f, 0.f, 0.f, 0.f);
    float ss = 0.f;
    if (lane < 49) {
        const int dy = lane / 7 - 3;
        const int dx = lane - (lane / 7) * 7 - 3;
        const int yy = clampi(qy + dy, H_ - 1);
        const int xx = clampi(qx + dx, W_ - 1);
        const float* p = deno + (size_t)qt * C_ * HW_ + yy * W_ + xx;
        const float a = p[0], b = p[HW_], c = p[2 * HW_];
        ss = fmaf(a, a, fmaf(b, b, c * c));
        qreg = make_float4(-2.f * a, -2.f * b, -2.f * c, 0.f);
        sQ[wave][lane] = qreg;
    }
    #pragma unroll
    for (int off = 32; off >= 1; off >>= 1) ss += __shfl_xor(ss, off, 64);
    const float qss = ss;

    // ---- stage both regions (deno @ ct0/ct1) with .w = sumsq ----
    const int rmin0 = clampi(cen_y0 - 7, H_ - 1);
    const int cmin0 = clampi(cen_x0 - 7, W_ - 1);
    const int rmin1 = clampi(cen_y1 - 7, H_ - 1);
    const int cmin1 = clampi(cen_x1 - 7, W_ - 1);
    const float* cfrm0 = deno  + (size_t)ct0 * C_ * HW_;
    const float* cfrm1 = deno  + (size_t)ct1 * C_ * HW_;
    const float* nfrm0 = noisy + (size_t)ct0 * C_ * HW_;
    const float* nfrm1 = noisy + (size_t)ct1 * C_ * HW_;

    int gidx[8], lidx[8];
    {
        int n = 0;
        for (int i = lane; i < 2 * R_ * R_; i += 64, ++n) {
            const int reg = (i >= R_ * R_);
            const int rem = i - reg * (R_ * R_);
            const int ry = rem / R_;
            const int rx = rem - ry * R_;
            int sy = (reg ? rmin1 : rmin0) + ry; if (sy > H_ - 1) sy = H_ - 1;
            int sx = (reg ? cmin1 : cmin0) + rx; if (sx > W_ - 1) sx = W_ - 1;
            gidx[n] = sy * W_ + sx;
            lidx[n] = reg * RRS_ + ry * RS_ + rx;
        }
        for (; n < 8; ++n) { gidx[n] = -1; lidx[n] = 0; }
    }
    #pragma unroll
    for (int n = 0; n < 8; ++n) {
        if (gidx[n] >= 0) {
            const float* f = (lidx[n] >= RRS_) ? cfrm1 : cfrm0;
            const int gi = gidx[n];
            float4 v;
            v.x = f[gi]; v.y = f[HW_ + gi]; v.z = f[2 * HW_ + gi];
            v.w = fmaf(v.x, v.x, fmaf(v.y, v.y, v.z * v.z));
            sR[wave][lidx[n]] = v;
        }
    }

    const char* R0 = (const char*)&sR[wave][0];
    const char* R1 = (const char*)&sR[wave][RRS_];
    const float4* Q4 = &sQ[wave][0];

    // ---- pass 1: window w = lane (0..63), both directions ----
    const int wy4p1 = lane / 9;            // w4 = wy' + 4 in [0,7]
    const int wx4p1 = lane - 9 * wy4p1;
    const unsigned rpA = iy0 ? mkpack_int(wy4p1) : mkpack_axis(cen_y0, wy4p1, rmin0);
    const unsigned cpA = ix0 ? mkpack_int(wx4p1) : mkpack_axis(cen_x0, wx4p1, cmin0);
    const unsigned rpB = iy1 ? mkpack_int(wy4p1) : mkpack_axis(cen_y1, wy4p1, rmin1);
    const unsigned cpB = ix1 ? mkpack_int(wx4p1) : mkpack_axis(cen_x1, wx4p1, cmin1);

    int colA[7], colB[7];   // byte offsets, dy-invariant
    #pragma unroll
    for (int dx = 0; dx < 7; ++dx) {
        colA[dx] = (int)((cpA >> (4 * dx)) & 15) * 16;
        colB[dx] = (int)((cpB >> (4 * dx)) & 15) * 16;
    }
    float u0 = 0.f, u1 = 0.f, u2 = 0.f, uw = 0.f;
    float v0 = 0.f, v1 = 0.f, v2 = 0.f, vw = 0.f;
    #pragma unroll 1
    for (int dy = 0; dy < 7; ++dy) {
        const char* rowA = R0 + ((rpA >> (4 * dy)) & 15) * (RS_ * 16);
        const char* rowB = R1 + ((rpB >> (4 * dy)) & 15) * (RS_ * 16);
        const int ob = dy * 7;
        #pragma unroll
        for (int dx = 0; dx < 7; ++dx) {
            const float m2qx = readlane_f(qreg.x, ob + dx);
            const float m2qy = readlane_f(qreg.y, ob + dx);
            const float m2qz = readlane_f(qreg.z, ob + dx);
            const float4 ca = *(const float4*)(rowA + colA[dx]);
            const float4 cb = *(const float4*)(rowB + colB[dx]);
            u0 = fmaf(ca.x, m2qx, u0); u1 = fmaf(ca.y, m2qy, u1);
            u2 = fmaf(ca.z, m2qz, u2); uw += ca.w;
            v0 = fmaf(cb.x, m2qx, v0); v1 = fmaf(cb.y, m2qy, v1);
            v2 = fmaf(cb.z, m2qz, v2); vw += cb.w;
        }
    }
    const float d1_0 = fmaxf(qss + (u0 + u1 + u2 + uw), 0.f);
    const float d1_1 = fmaxf(qss + (v0 + v1 + v2 + vw), 0.f);

    // ---- pass 2: windows 64..80, 3 lanes per window ----
    float d2_0 = 0.f, d2_1 = 0.f;
    const int w2   = 64 + lane / 3;          // valid for lane < 51
    const int part = lane - (lane / 3) * 3;
    if (lane < 51) {
        const int wy4 = w2 / 9;              // 7 or 8
        const int wx4 = w2 - 9 * wy4;
        const unsigned rp2A = iy0 ? mkpack_int(wy4) : mkpack_axis(cen_y0, wy4, rmin0);
        const unsigned cp2A = ix0 ? mkpack_int(wx4) : mkpack_axis(cen_x0, wx4, cmin0);
        const unsigned rp2B = iy1 ? mkpack_int(wy4) : mkpack_axis(cen_y1, wy4, rmin1);
        const unsigned cp2B = ix1 ? mkpack_int(wx4) : mkpack_axis(cen_x1, wx4, cmin1);
        float t0 = 0.f, t1 = 0.f, t2 = 0.f, tw = 0.f;
        float w0 = 0.f, w1 = 0.f, w2a = 0.f, ww = 0.f;
        int dyi = 0, dxi = part;             // o = part (<7), stride 3
        #pragma unroll 1
        for (int o = part; o < 49; o += 3) {
            const float4 qv = Q4[o];         // (-2q)
            const float4 ca = *(const float4*)(R0 + ((rp2A >> (4 * dyi)) & 15) * (RS_ * 16)
                                                  + ((cp2A >> (4 * dxi)) & 15) * 16);
            const float4 cb = *(const float4*)(R1 + ((rp2B >> (4 * dyi)) & 15) * (RS_ * 16)
                                                  + ((cp2B >> (4 * dxi)) & 15) * 16);
            t0 = fmaf(ca.x, qv.x, t0); t1 = fmaf(ca.y, qv.y, t1);
            t2 = fmaf(ca.z, qv.z, t2); tw += ca.w;
            w0 = fmaf(cb.x, qv.x, w0); w1 = fmaf(cb.y, qv.y, w1);
            w2a = fmaf(cb.z, qv.z, w2a); ww += cb.w;
            dxi += 3; if (dxi >= 7) { dxi -= 7; ++dyi; }
        }
        d2_0 = t0 + t1 + t2 + tw;
        d2_1 = w0 + w1 + w2a + ww;
    }
    const int base3 = lane * 3;
    const int g0 = base3 < 64 ? base3 : 0;
    const int g1 = base3 + 1 < 64 ? base3 + 1 : 0;
    const int g2 = base3 + 2 < 64 ? base3 + 2 : 0;
    const float dd0 = fmaxf(qss + __shfl(d2_0, g0) + __shfl(d2_0, g1) + __shfl(d2_0, g2), 0.f);
    const float dd1 = fmaxf(qss + __shfl(d2_1, g0) + __shfl(d2_1, g1) + __shfl(d2_1, g2), 0.f);

    // ---- restage both regions with noisy (.w = sumsq); wave-private ----
    #pragma unroll
    for (int n = 0; n < 8; ++n) {
        if (gidx[n] >= 0) {
            const float* f = (lidx[n] >= RRS_) ? nfrm1 : nfrm0;
            const int gi = gidx[n];
            float4 v;
            v.x = f[gi]; v.y = f[HW_ + gi]; v.z = f[2 * HW_ + gi];
            v.w = fmaf(v.x, v.x, fmaf(v.y, v.y, v.z * v.z));
            sR[wave][lidx[n]] = v;
        }
    }

    // ---- top-10 per direction via bitwise rank-select (VALU/SALU only) ----
    // keys: (dist_bits & ~0x7F) | w — monotone, unique, exact ties -> lower w.
    const unsigned kA0 = (__float_as_uint(d1_0) & 0xFFFFFF80u) | (unsigned)lane;
    const unsigned kA1 = (__float_as_uint(d1_1) & 0xFFFFFF80u) | (unsigned)lane;
    const unsigned kB0 = (lane < 17)
        ? ((__float_as_uint(dd0) & 0xFFFFFF80u) | (unsigned)(64 + lane)) : 0xFFFFFFFFu;
    const unsigned kB1 = (lane < 17)
        ? ((__float_as_uint(dd1) & 0xFFFFFF80u) | (unsigned)(64 + lane)) : 0xFFFFFFFFu;

    unsigned tau0 = 0, tau1 = 0;
    #pragma unroll
    for (int b = 30; b >= 0; --b) {   // bit 31 (sign) always 0 after fmax
        const unsigned t0v = tau0 | (1u << b);
        const unsigned t1v = tau1 | (1u << b);
        const int c0 = __popcll(__ballot(kA0 < t0v)) + __popcll(__ballot(kB0 < t0v));
        const int c1 = __popcll(__ballot(kA1 < t1v)) + __popcll(__ballot(kB1 < t1v));
        if (c0 <= 9) tau0 = t0v;
        if (c1 <= 9) tau1 = t1v;
    }
    {   // compact the 10 winners per direction (order within slots irrelevant)
        const bool sA0 = (kA0 <= tau0), sB0 = (kB0 <= tau0);
        const unsigned long long mA0 = __ballot(sA0), mB0 = __ballot(sB0);
        if (sA0) sSlot[wave][mbcnt64(mA0)] = kA0;
        if (sB0) sSlot[wave][__popcll(mA0) + mbcnt64(mB0)] = kB0;
        const bool sA1 = (kA1 <= tau1), sB1 = (kB1 <= tau1);
        const unsigned long long mA1 = __ballot(sA1), mB1 = __ballot(sB1);
        if (sA1) sSlot[wave][10 + mbcnt64(mA1)] = kA1;
        if (sB1) sSlot[wave][10 + __popcll(mA1) + mbcnt64(mB1)] = kB1;
    }

    const int sel = lane % 20;
    const unsigned myKey = sSlot[wave][sel];   // per-wave DS in-order
    const int   myW = (int)(myKey & 0x7Fu);
    const float myD = __uint_as_float(myKey & 0xFFFFFF80u);

    // ---- refine: dref = qss + sum(n.w - 2 q.n) over patch; mask per lane ----
    float partial = 0.f;
    if (lane < 60) {
        const int s1sel = (sel >= 10);
        const int ceny = s1sel ? cen_y1 : cen_y0;
        const int cenx = s1sel ? cen_x1 : cen_x0;
        const int rmr  = s1sel ? rmin1 : rmin0;
        const int cmr  = s1sel ? cmin1 : cmin0;
        const bool iyr = s1sel ? iy1 : iy0;
        const bool ixr = s1sel ? ix1 : ix0;
        const char* Nb = s1sel ? R1 : R0;
        const int wy4 = myW / 9;
        const int wx4 = myW - 9 * wy4;
        const unsigned rpR = iyr ? mkpack_int(wy4) : mkpack_axis(ceny, wy4, rmr);
        const unsigned cpR = ixr ? mkpack_int(wx4) : mkpack_axis(cenx, wx4, cmr);
        const int rpart = lane / 20;   // 0..2
        float t0 = 0.f, t1 = 0.f, t2 = 0.f, tw = 0.f;
        int dyi = 0, dxi = rpart;
        #pragma unroll 1
        for (int o = rpart; o < 49; o += 3) {
            const float4 qv = Q4[o];   // (-2q)
            const float4 nv = *(const float4*)(Nb + ((rpR >> (4 * dyi)) & 15) * (RS_ * 16)
                                                  + ((cpR >> (4 * dxi)) & 15) * 16);
            t0 = fmaf(nv.x, qv.x, t0); t1 = fmaf(nv.y, qv.y, t1);
            t2 = fmaf(nv.z, qv.z, t2); tw += nv.w;
            dxi += 3; if (dxi >= 7) { dxi -= 7; ++dyi; }
        }
        partial = t0 + t1 + t2 + tw;
        if (rpart == 0) partial += qss;   // qss once per selection
        // mask = (d0 / 147 < 0.5)  <=>  d0 < 73.5
        if (!(myD < 73.5f)) partial = 0.f;
    }
    #pragma unroll
    for (int off = 32; off >= 1; off >>= 1)
        partial += __shfl_xor(partial, off, 64);

    if (lane == 0)
        atomicAdd(&acc[q & (NSLOTS - 1)], partial * (1.0f / (float)TOTAL_SEL));
}

__global__ __launch_bounds__(64) void dnls_reduce(const float* __restrict__ acc,
                                                  float* __restrict__ out)
{
    const int lane = threadIdx.x;
    float v = 0.f;
    for (int i = lane; i < NSLOTS; i += 64) v += acc[i];
    #pragma unroll
    for (int off = 32; off >= 1; off >>= 1)
        v += __shfl_xor(v, off, 64);
    if (lane == 0) out[0] = v;
}

extern "C" void kernel_launch(void* const* d_in, const int* in_sizes, int n_in,
                              void* d_out, int out_size, void* d_ws, size_t ws_size,
                              hipStream_t stream) {
    const float* noisy = (const float*)d_in[0];
    const float* deno  = (const float*)d_in[2];
    const float* fflow = (const float*)d_in[3];
    const float* bflow = (const float*)d_in[4];
    float* out = (float*)d_out;
    float* acc = (float*)d_ws;

    hipMemsetAsync(acc, 0, NSLOTS * sizeof(float), stream);

    const int nblocks = QN_ / 4;   // one wave per query, 4 waves/block
    dnls_main<<<nblocks, 256, 0, stream>>>(noisy, deno, fflow, bflow, acc);
    dnls_reduce<<<1, 64, 0, stream>>>(acc, out);
}

// Round 11
// 436.666 us; speedup vs baseline: 7.4926x; 1.0592x over previous
//
#include <hip/hip_runtime.h>

#define T_ 5
#define C_ 3
#define H_ 128
#define W_ 128
#define HW_ (H_*W_)
#define WS_ 9
#define K_ 10
#define QN_ (T_*H_*W_)   // 81920
#define NSLOTS 1024
#define TOTAL_SEL (QN_ * 2 * K_)   // 1638400
#define R_ 15            // staged region side (window 9 + patch 7 - 1)
#define RS_ 17           // padded row stride in PIXELS (float4 each)
#define RRS_ (R_*RS_)    // 255 float4 per region

__device__ __forceinline__ int clampi(int v, int hi) {
    return v < 0 ? 0 : (v > hi ? hi : v);
}
__device__ __forceinline__ float readlane_f(float v, int l) {
    return __uint_as_float(__builtin_amdgcn_readlane(__float_as_uint(v), l));
}
__device__ __forceinline__ int mbcnt64(unsigned long long m) {
    return __builtin_amdgcn_mbcnt_hi((unsigned)(m >> 32),
           __builtin_amdgcn_mbcnt_lo((unsigned)m, 0));
}

// Border (slow) pack: nibble j = clamp(clamp(cen+w4-4)+j-3) - mn  (double clamp)
__device__ __forceinline__ unsigned mkpack_axis(int cen, int w4, int mn) {
    const int b = clampi(cen + w4 - 4, H_ - 1);
    unsigned r = 0;
    #pragma unroll
    for (int j = 0; j < 7; ++j)
        r |= (unsigned)(clampi(b + j - 3, H_ - 1) - mn) << (4 * j);
    return r;
}
// Interior fast pack (no clamp when 7 <= cen <= 120): nibble j = w4+j
__device__ __forceinline__ unsigned mkpack_int(int w4) {
    return (unsigned)w4 * 0x1111111u + 0x6543210u;
}

// One wave per query, both directions fused; all LDS wave-private, no
// __syncthreads. R9 post-mortem: VALU-bound (93%) but 104 MB/dispatch of
// scratch spill (gidx/lidx caches pushed demand past the VGPR=64 cap of
// __launch_bounds__(256,4)). R11 = R9 with staging geometry RECOMPUTED in
// both staging loops (no per-wave index arrays). Nothing else changed
// (bisect discipline after R10's unattributable NaN).
__global__ __launch_bounds__(256, 4) void dnls_main(
    const float* __restrict__ noisy,
    const float* __restrict__ deno,
    const float* __restrict__ fflow,
    const float* __restrict__ bflow,
    float* __restrict__ acc)
{
    __shared__ float4 sR[4][2 * RRS_];   // regions s0|s1: (rgb, sumsq); deno then noisy
    __shared__ float4 sQ[4][49];         // query patch as (-2q, 0)
    __shared__ unsigned sSlot[4][20];    // compacted top-k keys

    const int wave = threadIdx.x >> 6;
    const int lane = threadIdx.x & 63;
    const int q = blockIdx.x * 4 + wave;

    const int qt = q / HW_;
    const int qr = q - qt * HW_;
    const int qy = qr >> 7;
    const int qx = qr & 127;

    const int ct0 = (qt + 1 < T_) ? qt + 1 : T_ - 1;
    const int ct1 = (qt - 1 > 0) ? qt - 1 : 0;

    const int fidx = (qt * 2 * H_ + qy) * W_ + qx;
    const int cen_x0 = qx + (int)rintf(fflow[fidx]);
    const int cen_y0 = qy + (int)rintf(fflow[fidx + HW_]);
    const int cen_x1 = qx + (int)rintf(bflow[fidx]);
    const int cen_y1 = qy + (int)rintf(bflow[fidx + HW_]);

    const bool iy0 = (cen_y0 >= 7) && (cen_y0 <= H_ - 8);
    const bool ix0 = (cen_x0 >= 7) && (cen_x0 <= W_ - 8);
    const bool iy1 = (cen_y1 >= 7) && (cen_y1 <= H_ - 8);
    const bool ix1 = (cen_x1 >= 7) && (cen_x1 <= W_ - 8);

    // ---- query patch: lane o<49 holds (-2q); qss = sum q^2 (uniform) ----
    float4 qreg = make_float4(0.f, 0.f, 0.f, 0.f);
    float ss = 0.f;
    if (lane < 49) {
        const int dy = lane / 7 - 3;
        const int dx = lane - (lane / 7) * 7 - 3;
        const int yy = clampi(qy + dy, H_ - 1);
        const int xx = clampi(qx + dx, W_ - 1);
        const float* p = deno + (size_t)qt * C_ * HW_ + yy * W_ + xx;
        const float a = p[0], b = p[HW_], c = p[2 * HW_];
        ss = fmaf(a, a, fmaf(b, b, c * c));
        qreg = make_float4(-2.f * a, -2.f * b, -2.f * c, 0.f);
        sQ[wave][lane] = qreg;
    }
    #pragma unroll
    for (int off = 32; off >= 1; off >>= 1) ss += __shfl_xor(ss, off, 64);
    const float qss = ss;

    const int rmin0 = clampi(cen_y0 - 7, H_ - 1);
    const int cmin0 = clampi(cen_x0 - 7, W_ - 1);
    const int rmin1 = clampi(cen_y1 - 7, H_ - 1);
    const int cmin1 = clampi(cen_x1 - 7, W_ - 1);
    const float* cfrm0 = deno  + (size_t)ct0 * C_ * HW_;
    const float* cfrm1 = deno  + (size_t)ct1 * C_ * HW_;
    const float* nfrm0 = noisy + (size_t)ct0 * C_ * HW_;
    const float* nfrm1 = noisy + (size_t)ct1 * C_ * HW_;

    // ---- stage both regions (deno @ ct0/ct1), .w = sumsq; geometry
    // recomputed (NO cached index arrays -> no scratch spill) ----
    for (int i = lane; i < 2 * R_ * R_; i += 64) {
        const int reg = (i >= R_ * R_);
        const int rem = i - reg * (R_ * R_);
        const int ry = rem / R_;
        const int rx = rem - ry * R_;
        int sy = (reg ? rmin1 : rmin0) + ry; if (sy > H_ - 1) sy = H_ - 1;
        int sx = (reg ? cmin1 : cmin0) + rx; if (sx > W_ - 1) sx = W_ - 1;
        const int gi = sy * W_ + sx;
        const float* f = reg ? cfrm1 : cfrm0;
        float4 v;
        v.x = f[gi]; v.y = f[HW_ + gi]; v.z = f[2 * HW_ + gi];
        v.w = fmaf(v.x, v.x, fmaf(v.y, v.y, v.z * v.z));
        sR[wave][reg * RRS_ + ry * RS_ + rx] = v;
    }

    const char* R0 = (const char*)&sR[wave][0];
    const char* R1 = (const char*)&sR[wave][RRS_];
    const float4* Q4 = &sQ[wave][0];

    // ---- pass 1: window w = lane (0..63), both directions ----
    const int wy4p1 = lane / 9;
    const int wx4p1 = lane - 9 * wy4p1;
    const unsigned rpA = iy0 ? mkpack_int(wy4p1) : mkpack_axis(cen_y0, wy4p1, rmin0);
    const unsigned cpA = ix0 ? mkpack_int(wx4p1) : mkpack_axis(cen_x0, wx4p1, cmin0);
    const unsigned rpB = iy1 ? mkpack_int(wy4p1) : mkpack_axis(cen_y1, wy4p1, rmin1);
    const unsigned cpB = ix1 ? mkpack_int(wx4p1) : mkpack_axis(cen_x1, wx4p1, cmin1);

    int colA[7], colB[7];   // byte offsets, dy-invariant (dx fully unrolled)
    #pragma unroll
    for (int dx = 0; dx < 7; ++dx) {
        colA[dx] = (int)((cpA >> (4 * dx)) & 15) * 16;
        colB[dx] = (int)((cpB >> (4 * dx)) & 15) * 16;
    }
    float u0 = 0.f, u1 = 0.f, u2 = 0.f, uw = 0.f;
    float v0 = 0.f, v1 = 0.f, v2 = 0.f, vw = 0.f;
    #pragma unroll 1
    for (int dy = 0; dy < 7; ++dy) {
        const char* rowA = R0 + ((rpA >> (4 * dy)) & 15) * (RS_ * 16);
        const char* rowB = R1 + ((rpB >> (4 * dy)) & 15) * (RS_ * 16);
        const int ob = dy * 7;
        #pragma unroll
        for (int dx = 0; dx < 7; ++dx) {
            const float m2qx = readlane_f(qreg.x, ob + dx);
            const float m2qy = readlane_f(qreg.y, ob + dx);
            const float m2qz = readlane_f(qreg.z, ob + dx);
            const float4 ca = *(const float4*)(rowA + colA[dx]);
            const float4 cb = *(const float4*)(rowB + colB[dx]);
            u0 = fmaf(ca.x, m2qx, u0); u1 = fmaf(ca.y, m2qy, u1);
            u2 = fmaf(ca.z, m2qz, u2); uw += ca.w;
            v0 = fmaf(cb.x, m2qx, v0); v1 = fmaf(cb.y, m2qy, v1);
            v2 = fmaf(cb.z, m2qz, v2); vw += cb.w;
        }
    }
    const float d1_0 = fmaxf(qss + (u0 + u1 + u2 + uw), 0.f);
    const float d1_1 = fmaxf(qss + (v0 + v1 + v2 + vw), 0.f);

    // ---- pass 2: windows 64..80, 3 lanes per window ----
    float d2_0 = 0.f, d2_1 = 0.f;
    const int w2   = 64 + lane / 3;          // valid for lane < 51
    const int part = lane - (lane / 3) * 3;
    if (lane < 51) {
        const int wy4 = w2 / 9;              // 7 or 8
        const int wx4 = w2 - 9 * wy4;
        const unsigned rp2A = iy0 ? mkpack_int(wy4) : mkpack_axis(cen_y0, wy4, rmin0);
        const unsigned cp2A = ix0 ? mkpack_int(wx4) : mkpack_axis(cen_x0, wx4, cmin0);
        const unsigned rp2B = iy1 ? mkpack_int(wy4) : mkpack_axis(cen_y1, wy4, rmin1);
        const unsigned cp2B = ix1 ? mkpack_int(wx4) : mkpack_axis(cen_x1, wx4, cmin1);
        float t0 = 0.f, t1 = 0.f, t2 = 0.f, tw = 0.f;
        float w0 = 0.f, w1 = 0.f, w2a = 0.f, ww = 0.f;
        int dyi = 0, dxi = part;
        #pragma unroll 1
        for (int o = part; o < 49; o += 3) {
            const float4 qv = Q4[o];         // (-2q)
            const float4 ca = *(const float4*)(R0 + ((rp2A >> (4 * dyi)) & 15) * (RS_ * 16)
                                                  + ((cp2A >> (4 * dxi)) & 15) * 16);
            const float4 cb = *(const float4*)(R1 + ((rp2B >> (4 * dyi)) & 15) * (RS_ * 16)
                                                  + ((cp2B >> (4 * dxi)) & 15) * 16);
            t0 = fmaf(ca.x, qv.x, t0); t1 = fmaf(ca.y, qv.y, t1);
            t2 = fmaf(ca.z, qv.z, t2); tw += ca.w;
            w0 = fmaf(cb.x, qv.x, w0); w1 = fmaf(cb.y, qv.y, w1);
            w2a = fmaf(cb.z, qv.z, w2a); ww += cb.w;
            dxi += 3; if (dxi >= 7) { dxi -= 7; ++dyi; }
        }
        d2_0 = t0 + t1 + t2 + tw;
        d2_1 = w0 + w1 + w2a + ww;
    }
    const int base3 = lane * 3;
    const int g0 = base3 < 64 ? base3 : 0;
    const int g1 = base3 + 1 < 64 ? base3 + 1 : 0;
    const int g2 = base3 + 2 < 64 ? base3 + 2 : 0;
    const float dd0 = fmaxf(qss + __shfl(d2_0, g0) + __shfl(d2_0, g1) + __shfl(d2_0, g2), 0.f);
    const float dd1 = fmaxf(qss + __shfl(d2_1, g0) + __shfl(d2_1, g1) + __shfl(d2_1, g2), 0.f);

    // ---- restage with noisy (.w = sumsq); geometry recomputed ----
    for (int i = lane; i < 2 * R_ * R_; i += 64) {
        const int reg = (i >= R_ * R_);
        const int rem = i - reg * (R_ * R_);
        const int ry = rem / R_;
        const int rx = rem - ry * R_;
        int sy = (reg ? rmin1 : rmin0) + ry; if (sy > H_ - 1) sy = H_ - 1;
        int sx = (reg ? cmin1 : cmin0) + rx; if (sx > W_ - 1) sx = W_ - 1;
        const int gi = sy * W_ + sx;
        const float* f = reg ? nfrm1 : nfrm0;
        float4 v;
        v.x = f[gi]; v.y = f[HW_ + gi]; v.z = f[2 * HW_ + gi];
        v.w = fmaf(v.x, v.x, fmaf(v.y, v.y, v.z * v.z));
        sR[wave][reg * RRS_ + ry * RS_ + rx] = v;
    }

    // ---- top-10 per direction via bitwise rank-select (VALU/SALU only) ----
    const unsigned kA0 = (__float_as_uint(d1_0) & 0xFFFFFF80u) | (unsigned)lane;
    const unsigned kA1 = (__float_as_uint(d1_1) & 0xFFFFFF80u) | (unsigned)lane;
    const unsigned kB0 = (lane < 17)
        ? ((__float_as_uint(dd0) & 0xFFFFFF80u) | (unsigned)(64 + lane)) : 0xFFFFFFFFu;
    const unsigned kB1 = (lane < 17)
        ? ((__float_as_uint(dd1) & 0xFFFFFF80u) | (unsigned)(64 + lane)) : 0xFFFFFFFFu;

    unsigned tau0 = 0, tau1 = 0;
    #pragma unroll
    for (int b = 30; b >= 0; --b) {
        const unsigned t0v = tau0 | (1u << b);
        const unsigned t1v = tau1 | (1u << b);
        const int c0 = __popcll(__ballot(kA0 < t0v)) + __popcll(__ballot(kB0 < t0v));
        const int c1 = __popcll(__ballot(kA1 < t1v)) + __popcll(__ballot(kB1 < t1v));
        if (c0 <= 9) tau0 = t0v;
        if (c1 <= 9) tau1 = t1v;
    }
    {
        const bool sA0 = (kA0 <= tau0), sB0 = (kB0 <= tau0);
        const unsigned long long mA0 = __ballot(sA0), mB0 = __ballot(sB0);
        if (sA0) sSlot[wave][mbcnt64(mA0)] = kA0;
        if (sB0) sSlot[wave][__popcll(mA0) + mbcnt64(mB0)] = kB0;
        const bool sA1 = (kA1 <= tau1), sB1 = (kB1 <= tau1);
        const unsigned long long mA1 = __ballot(sA1), mB1 = __ballot(sB1);
        if (sA1) sSlot[wave][10 + mbcnt64(mA1)] = kA1;
        if (sB1) sSlot[wave][10 + __popcll(mA1) + mbcnt64(mB1)] = kB1;
    }

    const int sel = lane % 20;
    const unsigned myKey = sSlot[wave][sel];   // per-wave DS in-order
    const int   myW = (int)(myKey & 0x7Fu);
    const float myD = __uint_as_float(myKey & 0xFFFFFF80u);

    // ---- refine: dref = qss + sum(n.w - 2 q.n); mask per lane ----
    float partial = 0.f;
    if (lane < 60) {
        const int s1sel = (sel >= 10);
        const int ceny = s1sel ? cen_y1 : cen_y0;
        const int cenx = s1sel ? cen_x1 : cen_x0;
        const int rmr  = s1sel ? rmin1 : rmin0;
        const int cmr  = s1sel ? cmin1 : cmin0;
        const bool iyr = s1sel ? iy1 : iy0;
        const bool ixr = s1sel ? ix1 : ix0;
        const char* Nb = s1sel ? R1 : R0;
        const int wy4 = myW / 9;
        const int wx4 = myW - 9 * wy4;
        const unsigned rpR = iyr ? mkpack_int(wy4) : mkpack_axis(ceny, wy4, rmr);
        const unsigned cpR = ixr ? mkpack_int(wx4) : mkpack_axis(cenx, wx4, cmr);
        const int rpart = lane / 20;   // 0..2
        float t0 = 0.f, t1 = 0.f, t2 = 0.f, tw = 0.f;
        int dyi = 0, dxi = rpart;
        #pragma unroll 1
        for (int o = rpart; o < 49; o += 3) {
            const float4 qv = Q4[o];   // (-2q)
            const float4 nv = *(const float4*)(Nb + ((rpR >> (4 * dyi)) & 15) * (RS_ * 16)
                                                  + ((cpR >> (4 * dxi)) & 15) * 16);
            t0 = fmaf(nv.x, qv.x, t0); t1 = fmaf(nv.y, qv.y, t1);
            t2 = fmaf(nv.z, qv.z, t2); tw += nv.w;
            dxi += 3; if (dxi >= 7) { dxi -= 7; ++dyi; }
        }
        partial = t0 + t1 + t2 + tw;
        if (rpart == 0) partial += qss;   // qss once per selection
        if (!(myD < 73.5f)) partial = 0.f;   // mask: d0/147 < 0.5
    }
    #pragma unroll
    for (int off = 32; off >= 1; off >>= 1)
        partial += __shfl_xor(partial, off, 64);

    if (lane == 0)
        atomicAdd(&acc[q & (NSLOTS - 1)], partial * (1.0f / (float)TOTAL_SEL));
}

__global__ __launch_bounds__(64) void dnls_reduce(const float* __restrict__ acc,
                                                  float* __restrict__ out)
{
    const int lane = threadIdx.x;
    float v = 0.f;
    for (int i = lane; i < NSLOTS; i += 64) v += acc[i];
    #pragma unroll
    for (int off = 32; off >= 1; off >>= 1)
        v += __shfl_xor(v, off, 64);
    if (lane == 0) out[0] = v;
}

extern "C" void kernel_launch(void* const* d_in, const int* in_sizes, int n_in,
                              void* d_out, int out_size, void* d_ws, size_t ws_size,
                              hipStream_t stream) {
    const float* noisy = (const float*)d_in[0];
    const float* deno  = (const float*)d_in[2];
    const float* fflow = (const float*)d_in[3];
    const float* bflow = (const float*)d_in[4];
    float* out = (float*)d_out;
    float* acc = (float*)d_ws;

    hipMemsetAsync(acc, 0, NSLOTS * sizeof(float), stream);

    const int nblocks = QN_ / 4;   // one wave per query, 4 waves/block
    dnls_main<<<nblocks, 256, 0, stream>>>(noisy, deno, fflow, bflow, acc);
    dnls_reduce<<<1, 64, 0, stream>>>(acc, out);
}